// Round 1
// baseline (671.264 us; speedup 1.0000x reference)
//
#include <hip/hip_runtime.h>
#include <math.h>

// ---- workspace layout (float offsets) ----
#define WS_SRRP   0        // srr_pos[8000]  (atomic, zeroed)
#define WS_SRRN   8000     // srr_neg[8000]  (atomic, zeroed)
#define WS_WSUM   16000    // wsum_pos, wsum_neg (atomic, zeroed)
#define WS_GACC   16002    // g_acc[64] column-sum accumulator (atomic, zeroed)
#define ZERO_FLOATS 16066
#define WS_FCN    16128    // normalized fc [64]
#define WS_T1R    16192
#define WS_T1C    16256
#define WS_ALPHA  16320
#define WS_BETA   16384
#define WS_GAMMA  16448
#define WS_DELTA  16512
#define WS_ECP    16576
#define WS_ECN    16640
#define WS_W      16704    // w = t1r + theta2rc @ mu_c   [64]
#define WS_WRC    16768    // wrc[8000]
#define WS_FR     24768    // Fr normalized [8000*64]
#define WS_MU     536768   // mu_r stored as mu[v*64+p] = mu_r[p,v]  [8000*64]

__device__ __forceinline__ float waveReduceSum(float v) {
#pragma unroll
    for (int m = 32; m >= 1; m >>= 1) v += __shfl_xor(v, m, 64);
    return v;
}

// K1: all the small setup math (one wave).
__global__ __launch_bounds__(64) void k_setup(
    const float* __restrict__ A, const float* __restrict__ b, const float* __restrict__ c,
    const float* __restrict__ th1r, const float* __restrict__ th1c,
    const float* __restrict__ th2rc,
    const float* __restrict__ th3rr, const float* __restrict__ th3rc, const float* __restrict__ th3cr,
    const float* __restrict__ th4rr, const float* __restrict__ th4rc, const float* __restrict__ th4cr,
    const int* __restrict__ zp, float* __restrict__ ws)
{
    int p = threadIdx.x;
    __shared__ float fcraw[64], fz[64], sh4a[64], sh4b[64];
    int z = zp[0];

    float cv = (p < 63) ? c[p] : 0.f;          // fc_raw = [c, 0]
    float s = waveReduceSum(cv * cv);
    ws[WS_FCN + p] = cv * rsqrtf(s);
    fcraw[p] = cv;

    float av = (p < 63) ? A[z * 63 + p] : b[z]; // Fr_raw[z]
    float s2 = waveReduceSum(av * av);
    fz[p] = av * rsqrtf(s2);
    __syncthreads();

    float t1 = 0.f, t2 = 0.f, w0 = 0.f;
#pragma unroll 8
    for (int k = 0; k < 64; k++) {
        t1 += th1r[p * 64 + k] * fz[k];
        t2 += th1c[p * 64 + k] * fz[k];
        w0 += th2rc[p * 64 + k] * fcraw[k];   // theta2rc @ mu_c0 (raw fc)
    }
    ws[WS_T1R + p] = t1;
    ws[WS_T1C + p] = t2;
    ws[WS_W + p] = t1 + w0;                    // w for iteration 1

    sh4a[p] = th4rr[p];
    sh4b[p] = th4rc[p];
    __syncthreads();
    float a = 0.f, bb = 0.f, g = 0.f, d = 0.f;
#pragma unroll 8
    for (int k = 0; k < 64; k++) {
        float t4 = sh4a[k];
        a  += th3rr[p * 64 + k] * fmaxf(t4, 0.f);
        bb += th3rr[p * 64 + k] * fmaxf(-t4, 0.f);
        float t5 = sh4b[k];
        g  += th3rc[p * 64 + k] * fmaxf(t5, 0.f);
        d  += th3rc[p * 64 + k] * fmaxf(-t5, 0.f);
    }
    ws[WS_ALPHA + p] = a; ws[WS_BETA + p] = bb;
    ws[WS_GAMMA + p] = g; ws[WS_DELTA + p] = d;

    __syncthreads();
    sh4a[p] = th4cr[p];
    __syncthreads();
    float e1 = 0.f, e2 = 0.f;
#pragma unroll 8
    for (int k = 0; k < 64; k++) {
        float t6 = sh4a[k];
        e1 += th3cr[p * 64 + k] * fmaxf(t6, 0.f);
        e2 += th3cr[p * 64 + k] * fmaxf(-t6, 0.f);
    }
    ws[WS_ECP + p] = e1; ws[WS_ECN + p] = e2;
}

// K2: normalize rows -> Fr; write raw rows -> mu (init state); wrc; wsum atomics.
__global__ __launch_bounds__(256) void k_fr(
    const float* __restrict__ A, const float* __restrict__ b, float* __restrict__ ws)
{
    const float* fcn = ws + WS_FCN;
    float* Fr  = ws + WS_FR;
    float* mu  = ws + WS_MU;
    float* wrc = ws + WS_WRC;
    int lane = threadIdx.x & 63;
    int gw = blockIdx.x * 4 + (threadIdx.x >> 6);   // 0..499
    float fcv = fcn[lane];
    float lp = 0.f, ln = 0.f;
    for (int r = gw; r < 8000; r += 500) {
        float val = (lane < 63) ? A[r * 63 + lane] : b[r];
        float s = waveReduceSum(val * val);
        float f = val * rsqrtf(s);
        Fr[r * 64 + lane] = f;
        mu[r * 64 + lane] = val;                    // mu_r0 = Fr_raw^T
        float w = waveReduceSum(f * fcv);
        if (lane == 0) {
            wrc[r] = w;
            lp += fmaxf(w, 0.f);
            ln += fmaxf(-w, 0.f);
        }
    }
    if (lane == 0) {
        atomicAdd(ws + WS_WSUM, lp);
        atomicAdd(ws + WS_WSUM + 1, ln);
    }
}

// K3: the Gram row-sums. Block = 64 v-rows (in regs, one per lane) x u-chunk.
// grid (125, 8): blockIdx.x = v-tile, blockIdx.y = u-chunk phase.
__global__ __launch_bounds__(256) void k_gram(
    const float* __restrict__ Fr, float* __restrict__ ws)
{
    __shared__ float uT[64 * 64];     // 16KB staged u-tile
    __shared__ float red[512];
    int lane = threadIdx.x & 63;
    int wid  = threadIdx.x >> 6;
    int v = blockIdx.x * 64 + lane;

    float rv[64];
    const float4* vp = (const float4*)(Fr + v * 64);
#pragma unroll
    for (int i = 0; i < 16; i++) {
        float4 t = vp[i];
        rv[4*i] = t.x; rv[4*i+1] = t.y; rv[4*i+2] = t.z; rv[4*i+3] = t.w;
    }
    float accp = 0.f, accn = 0.f;

    for (int jt = blockIdx.y; jt < 125; jt += 8) {
        __syncthreads();
        const float4* src = (const float4*)(Fr + jt * 64 * 64);
        float4* dst = (float4*)uT;
#pragma unroll
        for (int i = 0; i < 4; i++) dst[threadIdx.x + 256 * i] = src[threadIdx.x + 256 * i];
        __syncthreads();
#pragma unroll 2
        for (int i = 0; i < 16; i++) {
            const float4* up = (const float4*)(uT + (wid * 16 + i) * 64);
            float g = 0.f;
#pragma unroll
            for (int kk = 0; kk < 16; kk++) {
                float4 u4 = up[kk];
                g += rv[4*kk] * u4.x + rv[4*kk+1] * u4.y + rv[4*kk+2] * u4.z + rv[4*kk+3] * u4.w;
            }
            accp += fmaxf(g, 0.f);
            accn += fmaxf(-g, 0.f);
        }
    }
    __syncthreads();
    red[wid * 64 + lane] = accp;
    red[256 + wid * 64 + lane] = accn;
    __syncthreads();
    if (threadIdx.x < 64) {
        float s = red[lane] + red[64 + lane] + red[128 + lane] + red[192 + lane];
        atomicAdd(ws + WS_SRRP + v, s);
    } else if (threadIdx.x < 128) {
        float s = red[256 + lane] + red[320 + lane] + red[384 + lane] + red[448 + lane];
        atomicAdd(ws + WS_SRRN + blockIdx.x * 64 + lane, s);
    }
}

// Kr: one recurrence sweep over row embeddings. grid 125 x 256.
// Column v = blockIdx.x*64 + lane (same 64 columns per block, each wave does 16 p-rows).
__global__ __launch_bounds__(256) void k_iter(
    const float* __restrict__ th2rr, float* __restrict__ ws)
{
    __shared__ float R[64 * 64];
    __shared__ float wv[64], al[64], be[64], ga[64], de[64];
    float* mu = ws + WS_MU;
    int lane = threadIdx.x & 63;
    int wid  = threadIdx.x >> 6;
    int v = blockIdx.x * 64 + lane;

    {
        const float4* src = (const float4*)th2rr;
        float4* dst = (float4*)R;
#pragma unroll
        for (int i = 0; i < 4; i++) dst[threadIdx.x + 256 * i] = src[threadIdx.x + 256 * i];
        if (threadIdx.x < 64) {
            int t = threadIdx.x;
            wv[t] = ws[WS_W + t];
            al[t] = ws[WS_ALPHA + t]; be[t] = ws[WS_BETA + t];
            ga[t] = ws[WS_GAMMA + t]; de[t] = ws[WS_DELTA + t];
        }
    }
    __syncthreads();

    float x[64];
    const float4* xp = (const float4*)(mu + v * 64);
#pragma unroll
    for (int i = 0; i < 16; i++) {
        float4 t = xp[i];
        x[4*i] = t.x; x[4*i+1] = t.y; x[4*i+2] = t.z; x[4*i+3] = t.w;
    }
    float sp = ws[WS_SRRP + v] - 1.0f;     // remove diagonal relu(1)=1
    float sn = ws[WS_SRRN + v];
    float wr = ws[WS_WRC + v];
    float rp = fmaxf(wr, 0.f), rn = fmaxf(-wr, 0.f);
    __syncthreads();   // all x loaded before anyone stores back into mu

    int p0 = wid * 16;
    float xn[16];
#pragma unroll
    for (int pi = 0; pi < 16; pi++) {
        int p = p0 + pi;
        float acc = wv[p] + al[p] * sp + be[p] * sn + ga[p] * rp + de[p] * rn;
        const float4* Rp = (const float4*)(R + p * 64);
#pragma unroll
        for (int kk = 0; kk < 16; kk++) {
            float4 r4 = Rp[kk];
            acc += r4.x * x[4*kk] + r4.y * x[4*kk+1] + r4.z * x[4*kk+2] + r4.w * x[4*kk+3];
        }
        xn[pi] = fmaxf(acc, 0.f);
    }
    float4* mup = (float4*)(mu + v * 64 + p0);
#pragma unroll
    for (int q = 0; q < 4; q++) {
        float4 t; t.x = xn[4*q]; t.y = xn[4*q+1]; t.z = xn[4*q+2]; t.w = xn[4*q+3];
        mup[q] = t;
    }
    // column sums -> g_acc
#pragma unroll
    for (int pi = 0; pi < 16; pi++) {
        float sv = xn[pi];
#pragma unroll
        for (int m = 32; m >= 1; m >>= 1) sv += __shfl_xor(sv, m, 64);
        if (lane == 0) atomicAdd(ws + WS_GACC + p0 + pi, sv);
    }
}

// Kc: column-node update (+ final head on the last iteration). 1 block, 64 threads.
__global__ __launch_bounds__(64) void k_col(
    const float* __restrict__ th2cr, const float* __restrict__ th2rc,
    const float* __restrict__ th6r, const float* __restrict__ th6c, const float* __restrict__ th7,
    const float* __restrict__ W8, const float* __restrict__ b8,
    const int* __restrict__ zp, float* __restrict__ ws, float* __restrict__ out, int last)
{
    int p = threadIdx.x;
    __shared__ float S[64], y[64], feat[128];
    float wsp = ws[WS_WSUM], wsn = ws[WS_WSUM + 1];
    S[p] = ws[WS_GACC + p];
    if (!last) ws[WS_GACC + p] = 0.f;     // reset accumulator for next sweep
    __syncthreads();

    float acc = ws[WS_T1C + p] + wsp * ws[WS_ECP + p] + wsn * ws[WS_ECN + p];
#pragma unroll 8
    for (int k = 0; k < 64; k++) acc += th2cr[p * 64 + k] * S[k];
    float yv = fmaxf(acc, 0.f);
    y[p] = yv;
    __syncthreads();

    float w = ws[WS_T1R + p];
#pragma unroll 8
    for (int k = 0; k < 64; k++) w += th2rc[p * 64 + k] * y[k];
    ws[WS_W + p] = w;

    if (last) {
        int z = zp[0];
        float t6 = 0.f, t7 = 0.f;
#pragma unroll 8
        for (int k = 0; k < 64; k++) {
            t6 += th6r[p * 64 + k] * S[k] + th6c[p * 64 + k] * y[k];
            t7 += th7[p * 64 + k] * ws[WS_MU + z * 64 + k];
        }
        feat[p] = 1.f / (1.f + expf(-t6));
        feat[64 + p] = 1.f / (1.f + expf(-t7));
        __syncthreads();
        if (p < 2) {
            float o = b8[p];
            for (int i = 0; i < 128; i++) o += W8[p * 128 + i] * feat[i];
            out[p] = o;
        }
    }
}

extern "C" void kernel_launch(void* const* d_in, const int* in_sizes, int n_in,
                              void* d_out, int out_size, void* d_ws, size_t ws_size,
                              hipStream_t stream) {
    (void)in_sizes; (void)n_in; (void)out_size; (void)ws_size;
    const float* A     = (const float*)d_in[0];
    const float* b     = (const float*)d_in[1];
    const float* c     = (const float*)d_in[2];
    const float* th1r  = (const float*)d_in[3];
    const float* th1c  = (const float*)d_in[4];
    const float* th2rr = (const float*)d_in[5];
    const float* th2rc = (const float*)d_in[6];
    const float* th2cr = (const float*)d_in[7];
    const float* th3rr = (const float*)d_in[8];
    const float* th3rc = (const float*)d_in[9];
    const float* th3cr = (const float*)d_in[10];
    const float* th4rr = (const float*)d_in[11];
    const float* th4rc = (const float*)d_in[12];
    const float* th4cr = (const float*)d_in[13];
    const float* th6r  = (const float*)d_in[14];
    const float* th6c  = (const float*)d_in[15];
    const float* th7   = (const float*)d_in[16];
    const float* W8    = (const float*)d_in[17];
    const float* b8    = (const float*)d_in[18];
    const int*   zp    = (const int*)d_in[19];
    float* ws  = (float*)d_ws;
    float* out = (float*)d_out;

    hipMemsetAsync(d_ws, 0, ZERO_FLOATS * sizeof(float), stream);
    k_setup<<<1, 64, 0, stream>>>(A, b, c, th1r, th1c, th2rc, th3rr, th3rc, th3cr,
                                  th4rr, th4rc, th4cr, zp, ws);
    k_fr<<<125, 256, 0, stream>>>(A, b, ws);
    k_gram<<<dim3(125, 8), 256, 0, stream>>>(ws + WS_FR, ws);
    for (int it = 0; it < 5; it++) {
        k_iter<<<125, 256, 0, stream>>>(th2rr, ws);
        k_col<<<1, 64, 0, stream>>>(th2cr, th2rc, th6r, th6c, th7, W8, b8, zp, ws, out, it == 4);
    }
}

// Round 3
// 581.415 us; speedup vs baseline: 1.1545x; 1.1545x over previous
//
#include <hip/hip_runtime.h>
#include <math.h>

typedef __attribute__((ext_vector_type(8))) short short8;
typedef __attribute__((ext_vector_type(4))) float f32x4;

// ---- workspace layout (float offsets) ----
#define WS_SRRP 0          // srr_pos_full[8000] (atomic, zeroed)
#define WS_WSUM 8000       // wsum_pos, wsum_neg (atomic, zeroed)
#define WS_G    8064       // g[64] = sum_v Fr[v] (atomic, zeroed)
#define WS_GACC 8128       // gacc[64] colsum accumulator (atomic, zeroed; reset by k_col)
#define ZERO_FLOATS 8192
#define WS_T1R  8192
#define WS_T1C  8256
#define WS_AL   8320
#define WS_BE   8384
#define WS_GA   8448
#define WS_DE   8512
#define WS_ECP  8576
#define WS_ECN  8640
#define WS_W    8704       // w = t1r + theta2rc @ mu_c [64]
#define WS_MU   8768       // mu state, mu[v*64+p] [8000*64] -> ends 520768
#define WS_FH   520768     // bf16 hi, ushort[8064*64]       -> ends 778816
#define WS_FL   778816     // bf16 lo, ushort[8064*64]       -> ends 1036864 (4.15 MB)
#define WS_E4   520768     // (sp,sn,rp,rn)[8000*4] overlays FH (dead after k_gram)

__device__ __forceinline__ float waveReduceSum(float v) {
#pragma unroll
    for (int m = 32; m >= 1; m >>= 1) v += __shfl_xor(v, m, 64);
    return v;
}
__device__ __forceinline__ unsigned short f2bf(float f) {
    unsigned int u = __float_as_uint(f);
    unsigned int r = (u + 0x7fffu + ((u >> 16) & 1u)) >> 16;
    return (unsigned short)r;
}
__device__ __forceinline__ float bf2f(unsigned short h) {
    return __uint_as_float(((unsigned int)h) << 16);
}

// K0: small setup math (one wave). Proven in round 1.
__global__ __launch_bounds__(64) void k_setup(
    const float* __restrict__ A, const float* __restrict__ b, const float* __restrict__ c,
    const float* __restrict__ th1r, const float* __restrict__ th1c,
    const float* __restrict__ th2rc,
    const float* __restrict__ th3rr, const float* __restrict__ th3rc, const float* __restrict__ th3cr,
    const float* __restrict__ th4rr, const float* __restrict__ th4rc, const float* __restrict__ th4cr,
    const int* __restrict__ zp, float* __restrict__ ws)
{
    int p = threadIdx.x;
    __shared__ float fcraw[64], fz[64], sh4a[64], sh4b[64];
    int z = zp[0];

    float cv = (p < 63) ? c[p] : 0.f;          // fc_raw = [c, 0]
    fcraw[p] = cv;

    float av = (p < 63) ? A[z * 63 + p] : b[z]; // Fr_raw[z]
    float s2 = waveReduceSum(av * av);
    fz[p] = av * rsqrtf(s2);
    __syncthreads();

    float t1 = 0.f, t2 = 0.f, w0 = 0.f;
#pragma unroll 8
    for (int k = 0; k < 64; k++) {
        t1 += th1r[p * 64 + k] * fz[k];
        t2 += th1c[p * 64 + k] * fz[k];
        w0 += th2rc[p * 64 + k] * fcraw[k];   // theta2rc @ mu_c0 (raw fc)
    }
    ws[WS_T1R + p] = t1;
    ws[WS_T1C + p] = t2;
    ws[WS_W + p] = t1 + w0;                    // w for sweep 1

    sh4a[p] = th4rr[p];
    sh4b[p] = th4rc[p];
    __syncthreads();
    float a = 0.f, bb = 0.f, g = 0.f, d = 0.f;
#pragma unroll 8
    for (int k = 0; k < 64; k++) {
        float t4 = sh4a[k];
        a  += th3rr[p * 64 + k] * fmaxf(t4, 0.f);
        bb += th3rr[p * 64 + k] * fmaxf(-t4, 0.f);
        float t5 = sh4b[k];
        g  += th3rc[p * 64 + k] * fmaxf(t5, 0.f);
        d  += th3rc[p * 64 + k] * fmaxf(-t5, 0.f);
    }
    ws[WS_AL + p] = a; ws[WS_BE + p] = bb;
    ws[WS_GA + p] = g; ws[WS_DE + p] = d;

    __syncthreads();
    sh4a[p] = th4cr[p];
    __syncthreads();
    float e1 = 0.f, e2 = 0.f;
#pragma unroll 8
    for (int k = 0; k < 64; k++) {
        float t6 = sh4a[k];
        e1 += th3cr[p * 64 + k] * fmaxf(t6, 0.f);
        e2 += th3cr[p * 64 + k] * fmaxf(-t6, 0.f);
    }
    ws[WS_ECP + p] = e1; ws[WS_ECN + p] = e2;
}

// K1: normalize rows, emit bf16 hi/lo, raw rows -> mu, g colsum, wsum. 125x256.
__global__ __launch_bounds__(256) void k_fr(
    const float* __restrict__ A, const float* __restrict__ b, const float* __restrict__ c,
    unsigned short* Fh, unsigned short* Fl, float* mu0, float* ws)
{
    __shared__ float gsh[64];
    __shared__ float wsh[2];
    int tid = threadIdx.x;
    int lane = tid & 63;
    int wid = tid >> 6;
    if (tid < 64) gsh[tid] = 0.f;
    if (tid < 2) wsh[tid] = 0.f;
    __syncthreads();

    float cv = (lane < 63) ? c[lane] : 0.f;
    float cn2 = waveReduceSum(cv * cv);
    float fcnl = cv * rsqrtf(cn2);

    int gw = blockIdx.x * 4 + wid;   // 0..499
    float gl = 0.f, lp = 0.f, ln = 0.f;
    for (int r = gw; r < 8000; r += 500) {
        float val = (lane < 63) ? A[r * 63 + lane] : b[r];
        float s2 = waveReduceSum(val * val);
        float f = val * rsqrtf(s2);
        mu0[r * 64 + lane] = val;
        unsigned short h = f2bf(f);
        float lo = f - bf2f(h);
        Fh[r * 64 + lane] = h;
        Fl[r * 64 + lane] = f2bf(lo);
        gl += f;
        float w = waveReduceSum(f * fcnl);
        if (lane == 0) { lp += fmaxf(w, 0.f); ln += fmaxf(-w, 0.f); }
    }
    atomicAdd(&gsh[lane], gl);
    if (lane == 0) { atomicAdd(&wsh[0], lp); atomicAdd(&wsh[1], ln); }
    __syncthreads();
    if (tid < 64) atomicAdd(ws + WS_G + tid, gsh[tid]);
    if (tid == 64) atomicAdd(ws + WS_WSUM, wsh[0]);
    if (tid == 65) atomicAdd(ws + WS_WSUM + 1, wsh[1]);

    if (blockIdx.x == 0) {   // zero-pad rows 8000..8063
        for (int idx = tid; idx < 64 * 64; idx += 256) {
            Fh[8000 * 64 + idx] = 0;
            Fl[8000 * 64 + idx] = 0;
        }
    }
}

// K2: MFMA gram row-sums, 16x16x32 bf16 (guide-verified layouts).
// grid (126, 8), block 256 (4 waves x 16 v-rows). A[m=lane&15][k=quad*8+j].
// C/D: col=lane&15 (u index), row=quad*4+reg (v-local index).
__global__ __launch_bounds__(256) void k_gram(
    const unsigned short* __restrict__ Fh, const unsigned short* __restrict__ Fl,
    float* __restrict__ ws)
{
    int lane = threadIdx.x & 63;
    int w = threadIdx.x >> 6;
    int m = lane & 15;
    int quad = lane >> 4;
    int v0 = blockIdx.x * 64 + w * 16;    // 126*64 = 8064 rows

    const unsigned short* pAH = Fh + (v0 + m) * 64 + quad * 8;
    const unsigned short* pAL = Fl + (v0 + m) * 64 + quad * 8;
    short8 Ah[2], Al[2];
#pragma unroll
    for (int q = 0; q < 2; q++) {        // K=64 split into two K=32 chunks
        Ah[q] = *(const short8*)(pAH + q * 32);
        Al[q] = *(const short8*)(pAL + q * 32);
    }
    float srr[4] = {0.f, 0.f, 0.f, 0.f};

    for (int j = blockIdx.y; j < 504; j += 8) {
        int u0 = j * 16;
        const unsigned short* pBH = Fh + (u0 + m) * 64 + quad * 8;
        const unsigned short* pBL = Fl + (u0 + m) * 64 + quad * 8;
        short8 Bh[2], Bl[2];
#pragma unroll
        for (int q = 0; q < 2; q++) {
            Bh[q] = *(const short8*)(pBH + q * 32);
            Bl[q] = *(const short8*)(pBL + q * 32);
        }
        f32x4 acc = {0.f, 0.f, 0.f, 0.f};
#pragma unroll
        for (int q = 0; q < 2; q++) {
            acc = __builtin_amdgcn_mfma_f32_16x16x32_bf16(Ah[q], Bh[q], acc, 0, 0, 0);
            acc = __builtin_amdgcn_mfma_f32_16x16x32_bf16(Ah[q], Bl[q], acc, 0, 0, 0);
            acc = __builtin_amdgcn_mfma_f32_16x16x32_bf16(Al[q], Bh[q], acc, 0, 0, 0);
            acc = __builtin_amdgcn_mfma_f32_16x16x32_bf16(Al[q], Bl[q], acc, 0, 0, 0);
        }
#pragma unroll
        for (int r = 0; r < 4; r++) srr[r] += fmaxf(acc[r], 0.f);
    }
    // sum over the 16 u-columns (lanes within quad), then atomic per v row
#pragma unroll
    for (int r = 0; r < 4; r++) {
        float s = srr[r];
#pragma unroll
        for (int mm = 8; mm >= 1; mm >>= 1) s += __shfl_xor(s, mm, 64);
        if (m == 0) {
            int row = v0 + quad * 4 + r;
            if (row < 8000) atomicAdd(ws + WS_SRRP + row, s);
        }
    }
}

// K3: one recurrence sweep. 125x256. first=1 also derives (sp,sn,rp,rn) -> E4.
__global__ __launch_bounds__(256) void k_iter(
    const float* __restrict__ th2rr, const float* __restrict__ c,
    float* __restrict__ ws, int first)
{
    __shared__ float R[4096];
    __shared__ float wv[64], al[64], be[64], ga[64], de[64], fcn[64], gsh[64];
    float* mu = ws + WS_MU;
    int tid = threadIdx.x;
    int lane = tid & 63;
    int wid = tid >> 6;
    int v = blockIdx.x * 64 + lane;

    {
        const float4* src = (const float4*)th2rr;
        float4* dst = (float4*)R;
#pragma unroll
        for (int i = 0; i < 4; i++) dst[tid + 256 * i] = src[tid + 256 * i];
    }
    if (wid == 0) {
        float cv = (lane < 63) ? c[lane] : 0.f;
        float cn2 = waveReduceSum(cv * cv);
        fcn[lane] = cv * rsqrtf(cn2);
    } else if (wid == 1) {
        gsh[lane] = ws[WS_G + lane];
    } else if (wid == 2) {
        wv[lane] = ws[WS_W + lane];
        al[lane] = ws[WS_AL + lane];
        be[lane] = ws[WS_BE + lane];
    } else {
        ga[lane] = ws[WS_GA + lane];
        de[lane] = ws[WS_DE + lane];
    }
    __syncthreads();

    float x[64];
    const float4* xp = (const float4*)(mu + v * 64);
#pragma unroll
    for (int i = 0; i < 16; i++) {
        float4 t = xp[i];
        x[4 * i] = t.x; x[4 * i + 1] = t.y; x[4 * i + 2] = t.z; x[4 * i + 3] = t.w;
    }
    float sp, sn, rp, rn;
    if (first) {
        float nrm = 0.f, dw = 0.f, dg = 0.f;
#pragma unroll 8
        for (int k = 0; k < 64; k++) {
            nrm += x[k] * x[k]; dw += x[k] * fcn[k]; dg += x[k] * gsh[k];
        }
        float rsn = rsqrtf(nrm);
        float wrc = dw * rsn;
        float spv = ws[WS_SRRP + v];
        sp = spv - 1.0f;            // remove diagonal relu(1)
        sn = spv - dg * rsn;        // relu(-x) = relu(x) - x identity
        rp = fmaxf(wrc, 0.f);
        rn = fmaxf(-wrc, 0.f);
        if (wid == 0) {
            float4 e; e.x = sp; e.y = sn; e.z = rp; e.w = rn;
            *(float4*)(ws + WS_E4 + v * 4) = e;
        }
    } else {
        float4 e = *(const float4*)(ws + WS_E4 + v * 4);
        sp = e.x; sn = e.y; rp = e.z; rn = e.w;
    }
    __syncthreads();   // all x loaded before anyone stores back into mu

    int p0 = wid * 16;
    float xn[16];
#pragma unroll
    for (int pi = 0; pi < 16; pi++) {
        int p = p0 + pi;
        float acc = wv[p] + al[p] * sp + be[p] * sn + ga[p] * rp + de[p] * rn;
        const float4* Rp = (const float4*)(R + p * 64);
#pragma unroll
        for (int kk = 0; kk < 16; kk++) {
            float4 r4 = Rp[kk];
            acc += r4.x * x[4 * kk] + r4.y * x[4 * kk + 1]
                 + r4.z * x[4 * kk + 2] + r4.w * x[4 * kk + 3];
        }
        xn[pi] = fmaxf(acc, 0.f);
    }
    float4* mup = (float4*)(mu + v * 64 + p0);
#pragma unroll
    for (int q = 0; q < 4; q++) {
        float4 t; t.x = xn[4*q]; t.y = xn[4*q+1]; t.z = xn[4*q+2]; t.w = xn[4*q+3];
        mup[q] = t;
    }
#pragma unroll
    for (int pi = 0; pi < 16; pi++) {
        float sv = waveReduceSum(xn[pi]);
        if (lane == 0) atomicAdd(ws + WS_GACC + p0 + pi, sv);
    }
}

// K4: column-node update (+ head on last). 1 block, 64 threads. Proven in round 1.
__global__ __launch_bounds__(64) void k_col(
    const float* __restrict__ th2cr, const float* __restrict__ th2rc,
    const float* __restrict__ th6r, const float* __restrict__ th6c, const float* __restrict__ th7,
    const float* __restrict__ W8, const float* __restrict__ b8,
    const int* __restrict__ zp, float* __restrict__ ws, float* __restrict__ out, int last)
{
    int p = threadIdx.x;
    __shared__ float S[64], y[64], feat[128];
    float wsp = ws[WS_WSUM], wsn = ws[WS_WSUM + 1];
    S[p] = ws[WS_GACC + p];
    if (!last) ws[WS_GACC + p] = 0.f;     // reset accumulator for next sweep
    __syncthreads();

    float acc = ws[WS_T1C + p] + wsp * ws[WS_ECP + p] + wsn * ws[WS_ECN + p];
#pragma unroll 8
    for (int k = 0; k < 64; k++) acc += th2cr[p * 64 + k] * S[k];
    float yv = fmaxf(acc, 0.f);
    y[p] = yv;
    __syncthreads();

    float w = ws[WS_T1R + p];
#pragma unroll 8
    for (int k = 0; k < 64; k++) w += th2rc[p * 64 + k] * y[k];
    ws[WS_W + p] = w;

    if (last) {
        int z = zp[0];
        float t6 = 0.f, t7 = 0.f;
#pragma unroll 8
        for (int k = 0; k < 64; k++) {
            t6 += th6r[p * 64 + k] * S[k] + th6c[p * 64 + k] * y[k];
            t7 += th7[p * 64 + k] * ws[WS_MU + z * 64 + k];
        }
        feat[p] = 1.f / (1.f + expf(-t6));
        feat[64 + p] = 1.f / (1.f + expf(-t7));
        __syncthreads();
        if (p < 2) {
            float o = b8[p];
            for (int i = 0; i < 128; i++) o += W8[p * 128 + i] * feat[i];
            out[p] = o;
        }
    }
}

extern "C" void kernel_launch(void* const* d_in, const int* in_sizes, int n_in,
                              void* d_out, int out_size, void* d_ws, size_t ws_size,
                              hipStream_t stream) {
    (void)in_sizes; (void)n_in; (void)out_size; (void)ws_size;
    const float* A     = (const float*)d_in[0];
    const float* b     = (const float*)d_in[1];
    const float* c     = (const float*)d_in[2];
    const float* th1r  = (const float*)d_in[3];
    const float* th1c  = (const float*)d_in[4];
    const float* th2rr = (const float*)d_in[5];
    const float* th2rc = (const float*)d_in[6];
    const float* th2cr = (const float*)d_in[7];
    const float* th3rr = (const float*)d_in[8];
    const float* th3rc = (const float*)d_in[9];
    const float* th3cr = (const float*)d_in[10];
    const float* th4rr = (const float*)d_in[11];
    const float* th4rc = (const float*)d_in[12];
    const float* th4cr = (const float*)d_in[13];
    const float* th6r  = (const float*)d_in[14];
    const float* th6c  = (const float*)d_in[15];
    const float* th7   = (const float*)d_in[16];
    const float* W8    = (const float*)d_in[17];
    const float* b8    = (const float*)d_in[18];
    const int*   zp    = (const int*)d_in[19];
    float* ws  = (float*)d_ws;
    float* out = (float*)d_out;
    unsigned short* Fh = (unsigned short*)(ws + WS_FH);
    unsigned short* Fl = (unsigned short*)(ws + WS_FL);
    float* mu0 = ws + WS_MU;

    hipMemsetAsync(d_ws, 0, ZERO_FLOATS * sizeof(float), stream);
    k_setup<<<1, 64, 0, stream>>>(A, b, c, th1r, th1c, th2rc, th3rr, th3rc, th3cr,
                                  th4rr, th4rc, th4cr, zp, ws);
    k_fr<<<125, 256, 0, stream>>>(A, b, c, Fh, Fl, mu0, ws);
    k_gram<<<dim3(126, 8), 256, 0, stream>>>(Fh, Fl, ws);
    for (int it = 0; it < 5; it++) {
        k_iter<<<125, 256, 0, stream>>>(th2rr, c, ws, it == 0);
        k_col<<<1, 64, 0, stream>>>(th2cr, th2rc, th6r, th6c, th7, W8, b8, zp, ws, out, it == 4);
    }
}

// Round 4
// 528.932 us; speedup vs baseline: 1.2691x; 1.0992x over previous
//
#include <hip/hip_runtime.h>
#include <math.h>

typedef __attribute__((ext_vector_type(8))) short short8;
typedef __attribute__((ext_vector_type(4))) float f32x4;

// ---- workspace layout (float offsets) ----
#define WS_SRRP 0          // srr_pos_full[8192] (atomic, zeroed)
#define WS_WSUM 8192       // wsum_pos, wsum_neg (atomic, zeroed)
#define WS_G    8256       // g[64] = sum_v Fr[v] (atomic, zeroed)
#define WS_GACC 8320       // gacc[5][64] per-sweep colsums (atomic, zeroed)
#define ZERO_FLOATS 8640
#define WS_T1R  8640
#define WS_T1C  8704
#define WS_AL   8768
#define WS_BE   8832
#define WS_GA   8896
#define WS_DE   8960
#define WS_ECP  9024
#define WS_ECN  9088
#define WS_W    9152       // w for sweep 0 (from setup)
#define WS_MUZ  9216       // final mu[:,z] [64]
#define WS_E4   9280       // (sp,sn,rp,rn)[8000*4] -> 41280
#define WS_MU0  41280      // raw rows fp32 [8000*64] -> 553280
#define WS_FH   553280     // bf16 hi of Fr, ushort[8192*64] -> 815424
#define WS_FL   815424     // bf16 lo of Fr, ushort[8192*64] -> 1077568
#define WS_MH   553280     // mu hi/lo overlay FH/FL (dead after k_gram)
#define WS_ML   815424

__device__ __forceinline__ float waveReduceSum(float v) {
#pragma unroll
    for (int m = 32; m >= 1; m >>= 1) v += __shfl_xor(v, m, 64);
    return v;
}
__device__ __forceinline__ unsigned short f2bf(float f) {
    unsigned int u = __float_as_uint(f);
    unsigned int r = (u + 0x7fffu + ((u >> 16) & 1u)) >> 16;
    return (unsigned short)r;
}
__device__ __forceinline__ float bf2f(unsigned short h) {
    return __uint_as_float(((unsigned int)h) << 16);
}

// K0: small setup math (one wave). Proven round 1/3.
__global__ __launch_bounds__(64) void k_setup(
    const float* __restrict__ A, const float* __restrict__ b, const float* __restrict__ c,
    const float* __restrict__ th1r, const float* __restrict__ th1c,
    const float* __restrict__ th2rc,
    const float* __restrict__ th3rr, const float* __restrict__ th3rc, const float* __restrict__ th3cr,
    const float* __restrict__ th4rr, const float* __restrict__ th4rc, const float* __restrict__ th4cr,
    const int* __restrict__ zp, float* __restrict__ ws)
{
    int p = threadIdx.x;
    __shared__ float fcraw[64], fz[64], sh4a[64], sh4b[64];
    int z = zp[0];

    float cv = (p < 63) ? c[p] : 0.f;
    fcraw[p] = cv;
    float av = (p < 63) ? A[z * 63 + p] : b[z];
    float s2 = waveReduceSum(av * av);
    fz[p] = av * rsqrtf(s2);
    __syncthreads();

    float t1 = 0.f, t2 = 0.f, w0 = 0.f;
#pragma unroll 8
    for (int k = 0; k < 64; k++) {
        t1 += th1r[p * 64 + k] * fz[k];
        t2 += th1c[p * 64 + k] * fz[k];
        w0 += th2rc[p * 64 + k] * fcraw[k];
    }
    ws[WS_T1R + p] = t1;
    ws[WS_T1C + p] = t2;
    ws[WS_W + p] = t1 + w0;

    sh4a[p] = th4rr[p];
    sh4b[p] = th4rc[p];
    __syncthreads();
    float a = 0.f, bb = 0.f, g = 0.f, d = 0.f;
#pragma unroll 8
    for (int k = 0; k < 64; k++) {
        float t4 = sh4a[k];
        a  += th3rr[p * 64 + k] * fmaxf(t4, 0.f);
        bb += th3rr[p * 64 + k] * fmaxf(-t4, 0.f);
        float t5 = sh4b[k];
        g  += th3rc[p * 64 + k] * fmaxf(t5, 0.f);
        d  += th3rc[p * 64 + k] * fmaxf(-t5, 0.f);
    }
    ws[WS_AL + p] = a; ws[WS_BE + p] = bb;
    ws[WS_GA + p] = g; ws[WS_DE + p] = d;

    __syncthreads();
    sh4a[p] = th4cr[p];
    __syncthreads();
    float e1 = 0.f, e2 = 0.f;
#pragma unroll 8
    for (int k = 0; k < 64; k++) {
        float t6 = sh4a[k];
        e1 += th3cr[p * 64 + k] * fmaxf(t6, 0.f);
        e2 += th3cr[p * 64 + k] * fmaxf(-t6, 0.f);
    }
    ws[WS_ECP + p] = e1; ws[WS_ECN + p] = e2;
}

// K1: normalize rows -> Fh/Fl (8192 padded), raw rows -> mu0, g, wsum. 128x256.
__global__ __launch_bounds__(256) void k_fr(
    const float* __restrict__ A, const float* __restrict__ b, const float* __restrict__ c,
    unsigned short* __restrict__ Fh, unsigned short* __restrict__ Fl,
    float* __restrict__ mu0, float* __restrict__ ws)
{
    __shared__ float gsh[64];
    __shared__ float wsh2[2];
    int tid = threadIdx.x, lane = tid & 63, wid = tid >> 6;
    if (tid < 64) gsh[tid] = 0.f;
    if (tid < 2) wsh2[tid] = 0.f;
    __syncthreads();

    float cv = (lane < 63) ? c[lane] : 0.f;
    float cn2 = waveReduceSum(cv * cv);
    float fcnl = cv * rsqrtf(cn2);

    int gw = blockIdx.x * 4 + wid;   // 0..511
    float gl = 0.f, lp = 0.f, ln = 0.f;
    for (int r = gw; r < 8192; r += 512) {
        if (r < 8000) {
            float val = (lane < 63) ? A[r * 63 + lane] : b[r];
            float s2 = waveReduceSum(val * val);
            float f = val * rsqrtf(s2);
            mu0[r * 64 + lane] = val;
            unsigned short h = f2bf(f);
            Fh[r * 64 + lane] = h;
            Fl[r * 64 + lane] = f2bf(f - bf2f(h));
            gl += f;
            float w = waveReduceSum(f * fcnl);
            if (lane == 0) { lp += fmaxf(w, 0.f); ln += fmaxf(-w, 0.f); }
        } else {
            Fh[r * 64 + lane] = 0;
            Fl[r * 64 + lane] = 0;
        }
    }
    atomicAdd(&gsh[lane], gl);
    if (lane == 0) { atomicAdd(&wsh2[0], lp); atomicAdd(&wsh2[1], ln); }
    __syncthreads();
    if (tid < 64) atomicAdd(ws + WS_G + tid, gsh[tid]);
    if (tid == 64) atomicAdd(ws + WS_WSUM, wsh2[0]);
    if (tid == 65) atomicAdd(ws + WS_WSUM + 1, wsh2[1]);
}

// K2: MFMA gram row-sums. grid (32,16), block 256. 64 v-rows/wave (4 tiles),
// B double-buffered, products HH+HL+LH (LL ~2^-18, dropped).
__global__ __launch_bounds__(256) void k_gram(
    const unsigned short* __restrict__ Fh, const unsigned short* __restrict__ Fl,
    float* __restrict__ ws)
{
    int tid = threadIdx.x, lane = tid & 63, wid = tid >> 6;
    int m = lane & 15, quad = lane >> 4;
    int vbase = blockIdx.x * 256 + wid * 64;

    short8 AH[8], AL[8];
#pragma unroll
    for (int pt = 0; pt < 4; pt++)
#pragma unroll
        for (int q = 0; q < 2; q++) {
            int off = (vbase + pt * 16 + m) * 64 + q * 32 + quad * 8;
            AH[pt * 2 + q] = *(const short8*)(Fh + off);
            AL[pt * 2 + q] = *(const short8*)(Fl + off);
        }
    float srr[16];
#pragma unroll
    for (int i = 0; i < 16; i++) srr[i] = 0.f;

    const int y = blockIdx.y;
    const int boff = m * 64 + quad * 8;
    short8 B0h[2], B0l[2], B1h[2], B1l[2];
#pragma unroll
    for (int q = 0; q < 2; q++) {
        B0h[q] = *(const short8*)(Fh + y * 16 * 64 + boff + q * 32);
        B0l[q] = *(const short8*)(Fl + y * 16 * 64 + boff + q * 32);
    }
#pragma unroll 1
    for (int ii = 0; ii < 16; ii++) {
        int jB = y + 32 * ii + 16;
#pragma unroll
        for (int q = 0; q < 2; q++) {
            B1h[q] = *(const short8*)(Fh + jB * 16 * 64 + boff + q * 32);
            B1l[q] = *(const short8*)(Fl + jB * 16 * 64 + boff + q * 32);
        }
#pragma unroll
        for (int pt = 0; pt < 4; pt++) {
            f32x4 a = {0.f, 0.f, 0.f, 0.f};
#pragma unroll
            for (int q = 0; q < 2; q++) {
                a = __builtin_amdgcn_mfma_f32_16x16x32_bf16(AH[pt*2+q], B0h[q], a, 0, 0, 0);
                a = __builtin_amdgcn_mfma_f32_16x16x32_bf16(AH[pt*2+q], B0l[q], a, 0, 0, 0);
                a = __builtin_amdgcn_mfma_f32_16x16x32_bf16(AL[pt*2+q], B0h[q], a, 0, 0, 0);
            }
#pragma unroll
            for (int r = 0; r < 4; r++) srr[pt*4+r] += fmaxf(a[r], 0.f);
        }
        if (ii < 15) {
            int jA = y + 32 * ii + 32;
#pragma unroll
            for (int q = 0; q < 2; q++) {
                B0h[q] = *(const short8*)(Fh + jA * 16 * 64 + boff + q * 32);
                B0l[q] = *(const short8*)(Fl + jA * 16 * 64 + boff + q * 32);
            }
        }
#pragma unroll
        for (int pt = 0; pt < 4; pt++) {
            f32x4 a = {0.f, 0.f, 0.f, 0.f};
#pragma unroll
            for (int q = 0; q < 2; q++) {
                a = __builtin_amdgcn_mfma_f32_16x16x32_bf16(AH[pt*2+q], B1h[q], a, 0, 0, 0);
                a = __builtin_amdgcn_mfma_f32_16x16x32_bf16(AH[pt*2+q], B1l[q], a, 0, 0, 0);
                a = __builtin_amdgcn_mfma_f32_16x16x32_bf16(AL[pt*2+q], B1h[q], a, 0, 0, 0);
            }
#pragma unroll
            for (int r = 0; r < 4; r++) srr[pt*4+r] += fmaxf(a[r], 0.f);
        }
    }
#pragma unroll
    for (int pt = 0; pt < 4; pt++)
#pragma unroll
        for (int r = 0; r < 4; r++) {
            float s = srr[pt * 4 + r];
#pragma unroll
            for (int mm = 8; mm >= 1; mm >>= 1) s += __shfl_xor(s, mm, 64);
            if (m == 0) atomicAdd(ws + WS_SRRP + vbase + pt * 16 + quad * 4 + r, s);
        }
}

// K2b: edge terms per row + bf16 hi/lo split of mu0. 125x64, thread = row.
__global__ __launch_bounds__(64) void k_e4(
    const float* __restrict__ c, float* __restrict__ ws,
    unsigned short* __restrict__ MH, unsigned short* __restrict__ ML)
{
    __shared__ float fcnS[64], gS[64];
    int lane = threadIdx.x;
    float cv = (lane < 63) ? c[lane] : 0.f;
    float cn2 = waveReduceSum(cv * cv);
    fcnS[lane] = cv * rsqrtf(cn2);
    gS[lane] = ws[WS_G + lane];
    __syncthreads();

    int v = blockIdx.x * 64 + lane;
    const float4* row = (const float4*)(ws + WS_MU0 + v * 64);
    float x[64];
#pragma unroll
    for (int i = 0; i < 16; i++) {
        float4 t = row[i];
        x[4*i] = t.x; x[4*i+1] = t.y; x[4*i+2] = t.z; x[4*i+3] = t.w;
    }
    float nrm = 0.f, dw = 0.f, dg = 0.f;
#pragma unroll 8
    for (int k = 0; k < 64; k++) {
        nrm += x[k] * x[k]; dw += x[k] * fcnS[k]; dg += x[k] * gS[k];
    }
    float rsn = rsqrtf(nrm);
    float wrc = dw * rsn;
    float spv = ws[WS_SRRP + v];
    float4 e;
    e.x = spv - 1.0f;           // sp: remove diagonal relu(1)
    e.y = spv - dg * rsn;       // sn via relu(-x) = relu(x) - x
    e.z = fmaxf(wrc, 0.f);
    e.w = fmaxf(-wrc, 0.f);
    *(float4*)(ws + WS_E4 + v * 4) = e;

#pragma unroll
    for (int i = 0; i < 16; i++) {
        ushort4 h4, l4;
        float x0 = x[4*i], x1 = x[4*i+1], x2 = x[4*i+2], x3 = x[4*i+3];
        h4.x = f2bf(x0); l4.x = f2bf(x0 - bf2f(h4.x));
        h4.y = f2bf(x1); l4.y = f2bf(x1 - bf2f(h4.y));
        h4.z = f2bf(x2); l4.z = f2bf(x2 - bf2f(h4.z));
        h4.w = f2bf(x3); l4.w = f2bf(x3 - bf2f(h4.w));
        *(ushort4*)(MH + v * 64 + 4 * i) = h4;
        *(ushort4*)(ML + v * 64 + 4 * i) = l4;
    }
}

// K3: one MFMA recurrence sweep, column-node update fused at head. 125x256.
__global__ __launch_bounds__(256) void k_iter(
    const float* __restrict__ th2rr, const float* __restrict__ th2cr,
    const float* __restrict__ th2rc, const int* __restrict__ zp,
    float* __restrict__ ws, unsigned short* __restrict__ MH,
    unsigned short* __restrict__ ML, int t)
{
    __shared__ __align__(16) float wsh[64], alS[64], beS[64], gaS[64], deS[64];
    __shared__ float Ssh[64], ysh[64];
    int tid = threadIdx.x, lane = tid & 63, wid = tid >> 6;
    int m = lane & 15, quad = lane >> 4;
    int v = (blockIdx.x * 4 + wid) * 16 + m;   // 125*4*16 = 8000 exactly

    if (tid < 64) {
        alS[tid] = ws[WS_AL + tid]; beS[tid] = ws[WS_BE + tid];
        gaS[tid] = ws[WS_GA + tid]; deS[tid] = ws[WS_DE + tid];
    }
    if (t == 0) {
        if (tid >= 64 && tid < 128) wsh[tid - 64] = ws[WS_W + tid - 64];
        __syncthreads();
    } else {
        if (tid >= 64 && tid < 128) Ssh[tid - 64] = ws[WS_GACC + (t - 1) * 64 + tid - 64];
        __syncthreads();
        if (tid < 64) {
            float acc = ws[WS_T1C + tid] + ws[WS_WSUM] * ws[WS_ECP + tid]
                      + ws[WS_WSUM + 1] * ws[WS_ECN + tid];
#pragma unroll 8
            for (int k = 0; k < 64; k++) acc += th2cr[tid * 64 + k] * Ssh[k];
            ysh[tid] = fmaxf(acc, 0.f);
        }
        __syncthreads();
        if (tid < 64) {
            float w = ws[WS_T1R + tid];
#pragma unroll 8
            for (int k = 0; k < 64; k++) w += th2rc[tid * 64 + k] * ysh[k];
            wsh[tid] = w;
        }
        __syncthreads();
    }

    // A-frags of th2rr (fp32 -> bf16 hi/lo), same layout as verified gram A
    short8 RH[8], RL[8];
#pragma unroll
    for (int pt = 0; pt < 4; pt++)
#pragma unroll
        for (int q = 0; q < 2; q++) {
            const float* rp = th2rr + (pt * 16 + m) * 64 + q * 32 + quad * 8;
            short8 H, L;
#pragma unroll
            for (int j = 0; j < 8; j++) {
                float f = rp[j];
                unsigned short h = f2bf(f);
                H[j] = (short)h;
                L[j] = (short)f2bf(f - bf2f(h));
            }
            RH[pt * 2 + q] = H; RL[pt * 2 + q] = L;
        }
    // B-frags: this wave's own 16 mu columns
    short8 BH[2], BL[2];
#pragma unroll
    for (int q = 0; q < 2; q++) {
        BH[q] = *(const short8*)(MH + v * 64 + q * 32 + quad * 8);
        BL[q] = *(const short8*)(ML + v * 64 + q * 32 + quad * 8);
    }
    float4 e = *(const float4*)(ws + WS_E4 + v * 4);
    int z = zp[0];

#pragma unroll
    for (int pt = 0; pt < 4; pt++) {
        f32x4 a = {0.f, 0.f, 0.f, 0.f};
#pragma unroll
        for (int q = 0; q < 2; q++) {
            a = __builtin_amdgcn_mfma_f32_16x16x32_bf16(RH[pt*2+q], BH[q], a, 0, 0, 0);
            a = __builtin_amdgcn_mfma_f32_16x16x32_bf16(RH[pt*2+q], BL[q], a, 0, 0, 0);
            a = __builtin_amdgcn_mfma_f32_16x16x32_bf16(RL[pt*2+q], BH[q], a, 0, 0, 0);
        }
        int pbase = pt * 16 + quad * 4;
        float4 w4 = *(const float4*)(wsh + pbase);
        float4 a4 = *(const float4*)(alS + pbase);
        float4 b4 = *(const float4*)(beS + pbase);
        float4 g4 = *(const float4*)(gaS + pbase);
        float4 d4 = *(const float4*)(deS + pbase);
        float v0 = fmaxf(a[0] + w4.x + a4.x*e.x + b4.x*e.y + g4.x*e.z + d4.x*e.w, 0.f);
        float v1 = fmaxf(a[1] + w4.y + a4.y*e.x + b4.y*e.y + g4.y*e.z + d4.y*e.w, 0.f);
        float v2 = fmaxf(a[2] + w4.z + a4.z*e.x + b4.z*e.y + g4.z*e.z + d4.z*e.w, 0.f);
        float v3 = fmaxf(a[3] + w4.w + a4.w*e.x + b4.w*e.y + g4.w*e.z + d4.w*e.w, 0.f);
        // store bf16 hi/lo for next sweep
        ushort4 h4, l4;
        h4.x = f2bf(v0); l4.x = f2bf(v0 - bf2f(h4.x));
        h4.y = f2bf(v1); l4.y = f2bf(v1 - bf2f(h4.y));
        h4.z = f2bf(v2); l4.z = f2bf(v2 - bf2f(h4.z));
        h4.w = f2bf(v3); l4.w = f2bf(v3 - bf2f(h4.w));
        *(ushort4*)(MH + v * 64 + pbase) = h4;
        *(ushort4*)(ML + v * 64 + pbase) = l4;
        // colsum over the tile's 16 v (lane bits 0..3), atomic into gacc[t]
        float c0 = v0, c1 = v1, c2 = v2, c3 = v3;
#pragma unroll
        for (int mm = 1; mm < 16; mm <<= 1) {
            c0 += __shfl_xor(c0, mm, 64);
            c1 += __shfl_xor(c1, mm, 64);
            c2 += __shfl_xor(c2, mm, 64);
            c3 += __shfl_xor(c3, mm, 64);
        }
        if (m == 0) {
            atomicAdd(ws + WS_GACC + t * 64 + pbase + 0, c0);
            atomicAdd(ws + WS_GACC + t * 64 + pbase + 1, c1);
            atomicAdd(ws + WS_GACC + t * 64 + pbase + 2, c2);
            atomicAdd(ws + WS_GACC + t * 64 + pbase + 3, c3);
        }
        if (t == 4 && v == z) {
            float4 o; o.x = v0; o.y = v1; o.z = v2; o.w = v3;
            *(float4*)(ws + WS_MUZ + pbase) = o;
        }
    }
}

// K4: final column update + head. 1 block, 64 threads.
__global__ __launch_bounds__(64) void k_head(
    const float* __restrict__ th2cr,
    const float* __restrict__ th6r, const float* __restrict__ th6c, const float* __restrict__ th7,
    const float* __restrict__ W8, const float* __restrict__ b8,
    float* __restrict__ ws, float* __restrict__ out)
{
    int p = threadIdx.x;
    __shared__ float S[64], y[64], feat[128];
    float wsp = ws[WS_WSUM], wsn = ws[WS_WSUM + 1];
    S[p] = ws[WS_GACC + 4 * 64 + p];
    __syncthreads();
    float acc = ws[WS_T1C + p] + wsp * ws[WS_ECP + p] + wsn * ws[WS_ECN + p];
#pragma unroll 8
    for (int k = 0; k < 64; k++) acc += th2cr[p * 64 + k] * S[k];
    y[p] = fmaxf(acc, 0.f);
    __syncthreads();
    float t6 = 0.f, t7 = 0.f;
#pragma unroll 8
    for (int k = 0; k < 64; k++) {
        t6 += th6r[p * 64 + k] * S[k] + th6c[p * 64 + k] * y[k];
        t7 += th7[p * 64 + k] * ws[WS_MUZ + k];
    }
    feat[p] = 1.f / (1.f + expf(-t6));
    feat[64 + p] = 1.f / (1.f + expf(-t7));
    __syncthreads();
    if (p < 2) {
        float o = b8[p];
        for (int i = 0; i < 128; i++) o += W8[p * 128 + i] * feat[i];
        out[p] = o;
    }
}

extern "C" void kernel_launch(void* const* d_in, const int* in_sizes, int n_in,
                              void* d_out, int out_size, void* d_ws, size_t ws_size,
                              hipStream_t stream) {
    (void)in_sizes; (void)n_in; (void)out_size; (void)ws_size;
    const float* A     = (const float*)d_in[0];
    const float* b     = (const float*)d_in[1];
    const float* c     = (const float*)d_in[2];
    const float* th1r  = (const float*)d_in[3];
    const float* th1c  = (const float*)d_in[4];
    const float* th2rr = (const float*)d_in[5];
    const float* th2rc = (const float*)d_in[6];
    const float* th2cr = (const float*)d_in[7];
    const float* th3rr = (const float*)d_in[8];
    const float* th3rc = (const float*)d_in[9];
    const float* th3cr = (const float*)d_in[10];
    const float* th4rr = (const float*)d_in[11];
    const float* th4rc = (const float*)d_in[12];
    const float* th4cr = (const float*)d_in[13];
    const float* th6r  = (const float*)d_in[14];
    const float* th6c  = (const float*)d_in[15];
    const float* th7   = (const float*)d_in[16];
    const float* W8    = (const float*)d_in[17];
    const float* b8    = (const float*)d_in[18];
    const int*   zp    = (const int*)d_in[19];
    float* ws  = (float*)d_ws;
    float* out = (float*)d_out;
    unsigned short* Fh = (unsigned short*)(ws + WS_FH);
    unsigned short* Fl = (unsigned short*)(ws + WS_FL);
    unsigned short* MH = (unsigned short*)(ws + WS_MH);
    unsigned short* ML = (unsigned short*)(ws + WS_ML);
    float* mu0 = ws + WS_MU0;

    hipMemsetAsync(d_ws, 0, ZERO_FLOATS * sizeof(float), stream);
    k_setup<<<1, 64, 0, stream>>>(A, b, c, th1r, th1c, th2rc, th3rr, th3rc, th3cr,
                                  th4rr, th4rc, th4cr, zp, ws);
    k_fr<<<128, 256, 0, stream>>>(A, b, c, Fh, Fl, mu0, ws);
    k_gram<<<dim3(32, 16), 256, 0, stream>>>(Fh, Fl, ws);
    k_e4<<<125, 64, 0, stream>>>(c, ws, MH, ML);
    for (int t = 0; t < 5; t++)
        k_iter<<<125, 256, 0, stream>>>(th2rr, th2cr, th2rc, zp, ws, MH, ML, t);
    k_head<<<1, 64, 0, stream>>>(th2cr, th6r, th6c, th7, W8, b8, ws, out);
}

// Round 5
// 240.195 us; speedup vs baseline: 2.7947x; 2.2021x over previous
//
#include <hip/hip_runtime.h>
#include <math.h>

typedef __attribute__((ext_vector_type(8))) short short8;
typedef __attribute__((ext_vector_type(4))) float f32x4;

// ---- workspace layout (float offsets) ----  total ~744704 floats = 2.98 MB
#define WS_SPART 0         // srr partials [16][8192]            -> 131072
#define WS_GPART 131072    // g partials  [128][64]              -> 139264
#define WS_WPART 139264    // wsum partials [128][2]             -> 139520
#define WS_CPART 139520    // colsum partials [5][125*64]        -> 179520
#define WS_T1R   179520
#define WS_T1C   179584
#define WS_AL    179648
#define WS_BE    179712
#define WS_GA    179776
#define WS_DE    179840
#define WS_ECP   179904
#define WS_ECN   179968
#define WS_W     180032    // w for sweep 0
#define WS_MUZ   180096    // final mu[:,z]
#define WS_WSUM  180160    // reduced wsum_pos/neg (written by k_e4)
#define WS_RNORM 180224    // row norms [8192]                   -> 188416
#define WS_E4    188416    // (sp,sn,rp,rn)[8000*4]              -> 220416
#define WS_FH    220416    // bf16 hi, ushort[8192*64] (mu hi overlays in-place after k_e4)
#define WS_FL    482560    // bf16 lo, ushort[8192*64]           -> 744704

__device__ __forceinline__ float waveReduceSum(float v) {
#pragma unroll
    for (int m = 32; m >= 1; m >>= 1) v += __shfl_xor(v, m, 64);
    return v;
}
__device__ __forceinline__ unsigned short f2bf(float f) {
    unsigned int u = __float_as_uint(f);
    unsigned int r = (u + 0x7fffu + ((u >> 16) & 1u)) >> 16;
    return (unsigned short)r;
}
__device__ __forceinline__ float bf2f(unsigned short h) {
    return __uint_as_float(((unsigned int)h) << 16);
}

// K1: blocks 0..127: normalize rows -> Fh/Fl + rnorm + g/wsum partials.
//     block 128: the small setup math (th1/th3/th4 contractions).
__global__ __launch_bounds__(256) void k_fr(
    const float* __restrict__ A, const float* __restrict__ b, const float* __restrict__ c,
    const float* __restrict__ th1r, const float* __restrict__ th1c,
    const float* __restrict__ th2rc,
    const float* __restrict__ th3rr, const float* __restrict__ th3rc, const float* __restrict__ th3cr,
    const float* __restrict__ th4rr, const float* __restrict__ th4rc, const float* __restrict__ th4cr,
    const int* __restrict__ zp,
    unsigned short* __restrict__ Fh, unsigned short* __restrict__ Fl,
    float* __restrict__ ws)
{
    int tid = threadIdx.x, lane = tid & 63, wid = tid >> 6;

    if (blockIdx.x == 128) {
        // ---- setup path (all 4 waves run it redundantly; benign same-value writes)
        __shared__ float fcraw[64], fz[64], sh4a[64], sh4b[64];
        int p = lane;
        int z = zp[0];
        float cv = (p < 63) ? c[p] : 0.f;
        fcraw[p] = cv;
        float av = (p < 63) ? A[z * 63 + p] : b[z];
        float s2 = waveReduceSum(av * av);
        fz[p] = av * rsqrtf(s2);
        __syncthreads();

        float t1 = 0.f, t2 = 0.f, w0 = 0.f;
#pragma unroll 8
        for (int k = 0; k < 64; k++) {
            t1 += th1r[p * 64 + k] * fz[k];
            t2 += th1c[p * 64 + k] * fz[k];
            w0 += th2rc[p * 64 + k] * fcraw[k];
        }
        ws[WS_T1R + p] = t1;
        ws[WS_T1C + p] = t2;
        ws[WS_W + p] = t1 + w0;

        sh4a[p] = th4rr[p];
        sh4b[p] = th4rc[p];
        __syncthreads();
        float a = 0.f, bb = 0.f, g = 0.f, d = 0.f;
#pragma unroll 8
        for (int k = 0; k < 64; k++) {
            float t4 = sh4a[k];
            a  += th3rr[p * 64 + k] * fmaxf(t4, 0.f);
            bb += th3rr[p * 64 + k] * fmaxf(-t4, 0.f);
            float t5 = sh4b[k];
            g  += th3rc[p * 64 + k] * fmaxf(t5, 0.f);
            d  += th3rc[p * 64 + k] * fmaxf(-t5, 0.f);
        }
        ws[WS_AL + p] = a; ws[WS_BE + p] = bb;
        ws[WS_GA + p] = g; ws[WS_DE + p] = d;
        __syncthreads();
        sh4a[p] = th4cr[p];
        __syncthreads();
        float e1 = 0.f, e2 = 0.f;
#pragma unroll 8
        for (int k = 0; k < 64; k++) {
            float t6 = sh4a[k];
            e1 += th3cr[p * 64 + k] * fmaxf(t6, 0.f);
            e2 += th3cr[p * 64 + k] * fmaxf(-t6, 0.f);
        }
        ws[WS_ECP + p] = e1; ws[WS_ECN + p] = e2;
        return;
    }

    // ---- row path
    __shared__ float gsh[64];
    __shared__ float wsh2[2];
    if (tid < 64) gsh[tid] = 0.f;
    if (tid < 2) wsh2[tid] = 0.f;
    __syncthreads();

    float cv = (lane < 63) ? c[lane] : 0.f;
    float cn2 = waveReduceSum(cv * cv);
    float fcnl = cv * rsqrtf(cn2);

    int gw = blockIdx.x * 4 + wid;   // 0..511
    float gl = 0.f, lp = 0.f, ln = 0.f;
    for (int r = gw; r < 8192; r += 512) {
        if (r < 8000) {
            float val = (lane < 63) ? A[r * 63 + lane] : b[r];
            float s2 = waveReduceSum(val * val);
            float f = val * rsqrtf(s2);
            unsigned short h = f2bf(f);
            Fh[r * 64 + lane] = h;
            Fl[r * 64 + lane] = f2bf(f - bf2f(h));
            gl += f;
            float w = waveReduceSum(f * fcnl);
            if (lane == 0) {
                ws[WS_RNORM + r] = sqrtf(s2);
                lp += fmaxf(w, 0.f); ln += fmaxf(-w, 0.f);
            }
        } else {
            Fh[r * 64 + lane] = 0;
            Fl[r * 64 + lane] = 0;
        }
    }
    atomicAdd(&gsh[lane], gl);                    // LDS atomics: 4-way, cheap
    if (lane == 0) { atomicAdd(&wsh2[0], lp); atomicAdd(&wsh2[1], ln); }
    __syncthreads();
    if (tid < 64) ws[WS_GPART + blockIdx.x * 64 + tid] = gsh[tid];
    if (tid == 64) ws[WS_WPART + blockIdx.x * 2 + 0] = wsh2[0];
    if (tid == 65) ws[WS_WPART + blockIdx.x * 2 + 1] = wsh2[1];
}

// K2: MFMA gram row-sums. grid (32,16), block 256. 64 v-rows/wave,
// B double-buffered, HH+HL+LH products. Partials -> SPART (no atomics).
__global__ __launch_bounds__(256) void k_gram(
    const unsigned short* __restrict__ Fh, const unsigned short* __restrict__ Fl,
    float* __restrict__ ws)
{
    int tid = threadIdx.x, lane = tid & 63, wid = tid >> 6;
    int m = lane & 15, quad = lane >> 4;
    int vbase = blockIdx.x * 256 + wid * 64;

    short8 AH[8], AL[8];
#pragma unroll
    for (int pt = 0; pt < 4; pt++)
#pragma unroll
        for (int q = 0; q < 2; q++) {
            int off = (vbase + pt * 16 + m) * 64 + q * 32 + quad * 8;
            AH[pt * 2 + q] = *(const short8*)(Fh + off);
            AL[pt * 2 + q] = *(const short8*)(Fl + off);
        }
    float srr[16];
#pragma unroll
    for (int i = 0; i < 16; i++) srr[i] = 0.f;

    const int y = blockIdx.y;
    const int boff = m * 64 + quad * 8;
    short8 B0h[2], B0l[2], B1h[2], B1l[2];
#pragma unroll
    for (int q = 0; q < 2; q++) {
        B0h[q] = *(const short8*)(Fh + y * 16 * 64 + boff + q * 32);
        B0l[q] = *(const short8*)(Fl + y * 16 * 64 + boff + q * 32);
    }
#pragma unroll 1
    for (int ii = 0; ii < 16; ii++) {
        int jB = y + 32 * ii + 16;
#pragma unroll
        for (int q = 0; q < 2; q++) {
            B1h[q] = *(const short8*)(Fh + jB * 16 * 64 + boff + q * 32);
            B1l[q] = *(const short8*)(Fl + jB * 16 * 64 + boff + q * 32);
        }
#pragma unroll
        for (int pt = 0; pt < 4; pt++) {
            f32x4 a = {0.f, 0.f, 0.f, 0.f};
#pragma unroll
            for (int q = 0; q < 2; q++) {
                a = __builtin_amdgcn_mfma_f32_16x16x32_bf16(AH[pt*2+q], B0h[q], a, 0, 0, 0);
                a = __builtin_amdgcn_mfma_f32_16x16x32_bf16(AH[pt*2+q], B0l[q], a, 0, 0, 0);
                a = __builtin_amdgcn_mfma_f32_16x16x32_bf16(AL[pt*2+q], B0h[q], a, 0, 0, 0);
            }
#pragma unroll
            for (int r = 0; r < 4; r++) srr[pt*4+r] += fmaxf(a[r], 0.f);
        }
        if (ii < 15) {
            int jA = y + 32 * ii + 32;
#pragma unroll
            for (int q = 0; q < 2; q++) {
                B0h[q] = *(const short8*)(Fh + jA * 16 * 64 + boff + q * 32);
                B0l[q] = *(const short8*)(Fl + jA * 16 * 64 + boff + q * 32);
            }
        }
#pragma unroll
        for (int pt = 0; pt < 4; pt++) {
            f32x4 a = {0.f, 0.f, 0.f, 0.f};
#pragma unroll
            for (int q = 0; q < 2; q++) {
                a = __builtin_amdgcn_mfma_f32_16x16x32_bf16(AH[pt*2+q], B1h[q], a, 0, 0, 0);
                a = __builtin_amdgcn_mfma_f32_16x16x32_bf16(AH[pt*2+q], B1l[q], a, 0, 0, 0);
                a = __builtin_amdgcn_mfma_f32_16x16x32_bf16(AL[pt*2+q], B1h[q], a, 0, 0, 0);
            }
#pragma unroll
            for (int r = 0; r < 4; r++) srr[pt*4+r] += fmaxf(a[r], 0.f);
        }
    }
#pragma unroll
    for (int pt = 0; pt < 4; pt++)
#pragma unroll
        for (int r = 0; r < 4; r++) {
            float s = srr[pt * 4 + r];
#pragma unroll
            for (int mm = 8; mm >= 1; mm >>= 1) s += __shfl_xor(s, mm, 64);
            if (m == 0)
                ws[WS_SPART + y * 8192 + vbase + pt * 16 + quad * 4 + r] = s;
        }
}

// K2b: reduce g/wsum/srr partials; edge terms; in-place mu hi/lo (raw rows).
// grid 125 x 64, thread = row.
__global__ __launch_bounds__(64) void k_e4(
    const float* __restrict__ c, float* __restrict__ ws,
    unsigned short* __restrict__ MH, unsigned short* __restrict__ ML)
{
    __shared__ float fcnS[64], gS[64];
    int lane = threadIdx.x;
    float cv = (lane < 63) ? c[lane] : 0.f;
    float cn2 = waveReduceSum(cv * cv);
    fcnS[lane] = cv * rsqrtf(cn2);

    float gv = 0.f;
#pragma unroll 8
    for (int blk = 0; blk < 128; blk++) gv += ws[WS_GPART + blk * 64 + lane];
    gS[lane] = gv;

    float wp = ws[WS_WPART + lane * 2] + ws[WS_WPART + (lane + 64) * 2];
    float wn = ws[WS_WPART + lane * 2 + 1] + ws[WS_WPART + (lane + 64) * 2 + 1];
    wp = waveReduceSum(wp); wn = waveReduceSum(wn);
    if (lane == 0) { ws[WS_WSUM] = wp; ws[WS_WSUM + 1] = wn; }  // same value from all blocks
    __syncthreads();

    int v = blockIdx.x * 64 + lane;
    float spv = 0.f;
#pragma unroll
    for (int y = 0; y < 16; y++) spv += ws[WS_SPART + y * 8192 + v];

    // reconstruct Fr row from hi+lo
    float fr[64];
#pragma unroll
    for (int i = 0; i < 8; i++) {
        short8 h8 = *(const short8*)(MH + v * 64 + i * 8);
        short8 l8 = *(const short8*)(ML + v * 64 + i * 8);
#pragma unroll
        for (int j = 0; j < 8; j++)
            fr[i * 8 + j] = bf2f((unsigned short)h8[j]) + bf2f((unsigned short)l8[j]);
    }
    float dw = 0.f, dg = 0.f;
#pragma unroll 8
    for (int k = 0; k < 64; k++) { dw += fr[k] * fcnS[k]; dg += fr[k] * gS[k]; }
    float4 e;
    e.x = spv - 1.0f;           // sp: remove diagonal relu(1)
    e.y = spv - dg;             // sn via relu(-x) = relu(x) - x
    e.z = fmaxf(dw, 0.f);
    e.w = fmaxf(-dw, 0.f);
    *(float4*)(ws + WS_E4 + v * 4) = e;

    // raw row = Fr * ||raw||; split hi/lo in place (same addresses, same thread)
    float rnv = ws[WS_RNORM + v];
#pragma unroll
    for (int i = 0; i < 16; i++) {
        ushort4 h4, l4;
        float x0 = fr[4*i] * rnv, x1 = fr[4*i+1] * rnv;
        float x2 = fr[4*i+2] * rnv, x3 = fr[4*i+3] * rnv;
        h4.x = f2bf(x0); l4.x = f2bf(x0 - bf2f(h4.x));
        h4.y = f2bf(x1); l4.y = f2bf(x1 - bf2f(h4.y));
        h4.z = f2bf(x2); l4.z = f2bf(x2 - bf2f(h4.z));
        h4.w = f2bf(x3); l4.w = f2bf(x3 - bf2f(h4.w));
        *(ushort4*)(MH + v * 64 + 4 * i) = h4;
        *(ushort4*)(ML + v * 64 + 4 * i) = l4;
    }
}

// K3: one MFMA recurrence sweep; colsum partials via LDS (no global atomics);
// column-node update of the PREVIOUS sweep fused into the prologue. 125x256.
__global__ __launch_bounds__(256) void k_iter(
    const float* __restrict__ th2rr, const float* __restrict__ th2cr,
    const float* __restrict__ th2rc, const int* __restrict__ zp,
    float* __restrict__ ws, unsigned short* __restrict__ MH,
    unsigned short* __restrict__ ML, int t)
{
    __shared__ __align__(16) float wsh[64], alS[64], beS[64], gaS[64], deS[64];
    __shared__ float red[256], Ssh[64], ysh[64], colp[256];
    int tid = threadIdx.x, lane = tid & 63, wid = tid >> 6;
    int m = lane & 15, quad = lane >> 4;
    int v = (blockIdx.x * 4 + wid) * 16 + m;   // 125*4*16 = 8000 exactly

    if (tid < 64) {
        alS[tid] = ws[WS_AL + tid]; beS[tid] = ws[WS_BE + tid];
        gaS[tid] = ws[WS_GA + tid]; deS[tid] = ws[WS_DE + tid];
    }
    if (t == 0) {
        if (tid >= 64 && tid < 128) wsh[tid - 64] = ws[WS_W + tid - 64];
        __syncthreads();
    } else {
        // reduce colsum partials of sweep t-1 (coalesced, all 256 threads)
        int p = lane;
        float s = 0.f;
        for (int blk = wid; blk < 125; blk += 4)
            s += ws[WS_CPART + (t - 1) * 8000 + blk * 64 + p];
        red[wid * 64 + p] = s;
        __syncthreads();
        if (tid < 64) Ssh[tid] = red[tid] + red[64 + tid] + red[128 + tid] + red[192 + tid];
        __syncthreads();
        if (tid < 64) {
            float acc = ws[WS_T1C + tid] + ws[WS_WSUM] * ws[WS_ECP + tid]
                      + ws[WS_WSUM + 1] * ws[WS_ECN + tid];
#pragma unroll 8
            for (int k = 0; k < 64; k++) acc += th2cr[tid * 64 + k] * Ssh[k];
            ysh[tid] = fmaxf(acc, 0.f);
        }
        __syncthreads();
        if (tid < 64) {
            float w = ws[WS_T1R + tid];
#pragma unroll 8
            for (int k = 0; k < 64; k++) w += th2rc[tid * 64 + k] * ysh[k];
            wsh[tid] = w;
        }
        __syncthreads();
    }

    // A-frags of th2rr (fp32 -> bf16 hi/lo)
    short8 RH[8], RL[8];
#pragma unroll
    for (int pt = 0; pt < 4; pt++)
#pragma unroll
        for (int q = 0; q < 2; q++) {
            const float* rp = th2rr + (pt * 16 + m) * 64 + q * 32 + quad * 8;
            short8 H, L;
#pragma unroll
            for (int j = 0; j < 8; j++) {
                float f = rp[j];
                unsigned short h = f2bf(f);
                H[j] = (short)h;
                L[j] = (short)f2bf(f - bf2f(h));
            }
            RH[pt * 2 + q] = H; RL[pt * 2 + q] = L;
        }
    // B-frags: this wave's own 16 mu columns
    short8 BH[2], BL[2];
#pragma unroll
    for (int q = 0; q < 2; q++) {
        BH[q] = *(const short8*)(MH + v * 64 + q * 32 + quad * 8);
        BL[q] = *(const short8*)(ML + v * 64 + q * 32 + quad * 8);
    }
    float4 e = *(const float4*)(ws + WS_E4 + v * 4);
    int z = zp[0];

#pragma unroll
    for (int pt = 0; pt < 4; pt++) {
        f32x4 a = {0.f, 0.f, 0.f, 0.f};
#pragma unroll
        for (int q = 0; q < 2; q++) {
            a = __builtin_amdgcn_mfma_f32_16x16x32_bf16(RH[pt*2+q], BH[q], a, 0, 0, 0);
            a = __builtin_amdgcn_mfma_f32_16x16x32_bf16(RH[pt*2+q], BL[q], a, 0, 0, 0);
            a = __builtin_amdgcn_mfma_f32_16x16x32_bf16(RL[pt*2+q], BH[q], a, 0, 0, 0);
        }
        int pbase = pt * 16 + quad * 4;
        float4 w4 = *(const float4*)(wsh + pbase);
        float4 a4 = *(const float4*)(alS + pbase);
        float4 b4 = *(const float4*)(beS + pbase);
        float4 g4 = *(const float4*)(gaS + pbase);
        float4 d4 = *(const float4*)(deS + pbase);
        float v0 = fmaxf(a[0] + w4.x + a4.x*e.x + b4.x*e.y + g4.x*e.z + d4.x*e.w, 0.f);
        float v1 = fmaxf(a[1] + w4.y + a4.y*e.x + b4.y*e.y + g4.y*e.z + d4.y*e.w, 0.f);
        float v2 = fmaxf(a[2] + w4.z + a4.z*e.x + b4.z*e.y + g4.z*e.z + d4.z*e.w, 0.f);
        float v3 = fmaxf(a[3] + w4.w + a4.w*e.x + b4.w*e.y + g4.w*e.z + d4.w*e.w, 0.f);
        // store bf16 hi/lo for next sweep
        ushort4 h4, l4;
        h4.x = f2bf(v0); l4.x = f2bf(v0 - bf2f(h4.x));
        h4.y = f2bf(v1); l4.y = f2bf(v1 - bf2f(h4.y));
        h4.z = f2bf(v2); l4.z = f2bf(v2 - bf2f(h4.z));
        h4.w = f2bf(v3); l4.w = f2bf(v3 - bf2f(h4.w));
        *(ushort4*)(MH + v * 64 + pbase) = h4;
        *(ushort4*)(ML + v * 64 + pbase) = l4;
        // colsum over this tile's 16 columns -> LDS stage
        float c0 = v0, c1 = v1, c2 = v2, c3 = v3;
#pragma unroll
        for (int mm = 1; mm < 16; mm <<= 1) {
            c0 += __shfl_xor(c0, mm, 64);
            c1 += __shfl_xor(c1, mm, 64);
            c2 += __shfl_xor(c2, mm, 64);
            c3 += __shfl_xor(c3, mm, 64);
        }
        if (m == 0) {
            colp[wid * 64 + pbase + 0] = c0;
            colp[wid * 64 + pbase + 1] = c1;
            colp[wid * 64 + pbase + 2] = c2;
            colp[wid * 64 + pbase + 3] = c3;
        }
        if (t == 4 && v == z) {
            float4 o; o.x = v0; o.y = v1; o.z = v2; o.w = v3;
            *(float4*)(ws + WS_MUZ + pbase) = o;
        }
    }
    __syncthreads();
    if (tid < 64)
        ws[WS_CPART + t * 8000 + blockIdx.x * 64 + tid] =
            colp[tid] + colp[64 + tid] + colp[128 + tid] + colp[192 + tid];
}

// K4: reduce last colsum partials + final column update + head. 1x64.
__global__ __launch_bounds__(64) void k_head(
    const float* __restrict__ th2cr,
    const float* __restrict__ th6r, const float* __restrict__ th6c, const float* __restrict__ th7,
    const float* __restrict__ W8, const float* __restrict__ b8,
    float* __restrict__ ws, float* __restrict__ out)
{
    int p = threadIdx.x;
    __shared__ float S[64], y[64], feat[128];
    float s = 0.f;
#pragma unroll 8
    for (int blk = 0; blk < 125; blk++) s += ws[WS_CPART + 4 * 8000 + blk * 64 + p];
    S[p] = s;
    __syncthreads();
    float acc = ws[WS_T1C + p] + ws[WS_WSUM] * ws[WS_ECP + p]
              + ws[WS_WSUM + 1] * ws[WS_ECN + p];
#pragma unroll 8
    for (int k = 0; k < 64; k++) acc += th2cr[p * 64 + k] * S[k];
    y[p] = fmaxf(acc, 0.f);
    __syncthreads();
    float t6 = 0.f, t7 = 0.f;
#pragma unroll 8
    for (int k = 0; k < 64; k++) {
        t6 += th6r[p * 64 + k] * S[k] + th6c[p * 64 + k] * y[k];
        t7 += th7[p * 64 + k] * ws[WS_MUZ + k];
    }
    feat[p] = 1.f / (1.f + expf(-t6));
    feat[64 + p] = 1.f / (1.f + expf(-t7));
    __syncthreads();
    if (p < 2) {
        float o = b8[p];
        for (int i = 0; i < 128; i++) o += W8[p * 128 + i] * feat[i];
        out[p] = o;
    }
}

extern "C" void kernel_launch(void* const* d_in, const int* in_sizes, int n_in,
                              void* d_out, int out_size, void* d_ws, size_t ws_size,
                              hipStream_t stream) {
    (void)in_sizes; (void)n_in; (void)out_size; (void)ws_size;
    const float* A     = (const float*)d_in[0];
    const float* b     = (const float*)d_in[1];
    const float* c     = (const float*)d_in[2];
    const float* th1r  = (const float*)d_in[3];
    const float* th1c  = (const float*)d_in[4];
    const float* th2rr = (const float*)d_in[5];
    const float* th2rc = (const float*)d_in[6];
    const float* th2cr = (const float*)d_in[7];
    const float* th3rr = (const float*)d_in[8];
    const float* th3rc = (const float*)d_in[9];
    const float* th3cr = (const float*)d_in[10];
    const float* th4rr = (const float*)d_in[11];
    const float* th4rc = (const float*)d_in[12];
    const float* th4cr = (const float*)d_in[13];
    const float* th6r  = (const float*)d_in[14];
    const float* th6c  = (const float*)d_in[15];
    const float* th7   = (const float*)d_in[16];
    const float* W8    = (const float*)d_in[17];
    const float* b8    = (const float*)d_in[18];
    const int*   zp    = (const int*)d_in[19];
    float* ws  = (float*)d_ws;
    float* out = (float*)d_out;
    unsigned short* Fh = (unsigned short*)(ws + WS_FH);
    unsigned short* Fl = (unsigned short*)(ws + WS_FL);

    k_fr<<<129, 256, 0, stream>>>(A, b, c, th1r, th1c, th2rc, th3rr, th3rc, th3cr,
                                  th4rr, th4rc, th4cr, zp, Fh, Fl, ws);
    k_gram<<<dim3(32, 16), 256, 0, stream>>>(Fh, Fl, ws);
    k_e4<<<125, 64, 0, stream>>>(c, ws, Fh, Fl);
    for (int t = 0; t < 5; t++)
        k_iter<<<125, 256, 0, stream>>>(th2rr, th2cr, th2rc, zp, ws, Fh, Fl, t);
    k_head<<<1, 64, 0, stream>>>(th2cr, th6r, th6c, th7, W8, b8, ws, out);
}

// Round 6
// 238.065 us; speedup vs baseline: 2.8197x; 1.0089x over previous
//
#include <hip/hip_runtime.h>
#include <math.h>

typedef __attribute__((ext_vector_type(8))) short short8;
typedef __attribute__((ext_vector_type(4))) float f32x4;

// ---- workspace layout (float offsets) ---- total 879872 floats = 3.52 MB
#define WS_SPART 0         // srr partials [32][8192]            -> 262144
#define WS_GPART 262144    // g partials [128][64]               -> 270336
#define WS_WPART 270336    // wsum partials [128][2]             -> 270592
#define WS_CPART 270592    // colsum partials [5][125*64]        -> 310592
#define WS_T1R   310592
#define WS_T1C   310656
#define WS_AL    310720
#define WS_BE    310784
#define WS_GA    310848
#define WS_DE    310912
#define WS_ECP   310976
#define WS_ECN   311040
#define WS_W     311104    // w for sweep 0
#define WS_MUZ   311168    // final mu[:,z]
#define WS_WSUM  311232    // reduced wsum_pos/neg (pad to 64)
#define WS_RNORM 311296    // row norms [8192]                   -> 319488
#define WS_R2H   319488    // th2rr bf16 hi, ushort[4096]        -> 321536
#define WS_R2L   321536    // th2rr bf16 lo, ushort[4096]        -> 323584
#define WS_E4    323584    // (sp,sn,rp,rn)[8000*4]              -> 355584
#define WS_FH    355584    // bf16 hi, ushort[8192*64] (mu overlays in place)
#define WS_FL    617728    //                                    -> 879872

__device__ __forceinline__ float waveReduceSum(float v) {
#pragma unroll
    for (int m = 32; m >= 1; m >>= 1) v += __shfl_xor(v, m, 64);
    return v;
}
__device__ __forceinline__ unsigned short f2bf(float f) {
    unsigned int u = __float_as_uint(f);
    unsigned int r = (u + 0x7fffu + ((u >> 16) & 1u)) >> 16;
    return (unsigned short)r;
}
__device__ __forceinline__ float bf2f(unsigned short h) {
    return __uint_as_float(((unsigned int)h) << 16);
}

// K1: blocks 0..127: normalize rows -> Fh/Fl + rnorm + g/wsum partials.
//     block 128: setup math + th2rr bf16 hi/lo conversion.
__global__ __launch_bounds__(256) void k_fr(
    const float* __restrict__ A, const float* __restrict__ b, const float* __restrict__ c,
    const float* __restrict__ th1r, const float* __restrict__ th1c,
    const float* __restrict__ th2rr, const float* __restrict__ th2rc,
    const float* __restrict__ th3rr, const float* __restrict__ th3rc, const float* __restrict__ th3cr,
    const float* __restrict__ th4rr, const float* __restrict__ th4rc, const float* __restrict__ th4cr,
    const int* __restrict__ zp,
    unsigned short* __restrict__ Fh, unsigned short* __restrict__ Fl,
    unsigned short* __restrict__ R2H, unsigned short* __restrict__ R2L,
    float* __restrict__ ws)
{
    int tid = threadIdx.x, lane = tid & 63, wid = tid >> 6;

    if (blockIdx.x == 128) {
        __shared__ float fcraw[64], fz[64], sh4a[64], sh4b[64];
        int p = lane;
        int z = zp[0];
        float cv = (p < 63) ? c[p] : 0.f;
        fcraw[p] = cv;
        float av = (p < 63) ? A[z * 63 + p] : b[z];
        float s2 = waveReduceSum(av * av);
        fz[p] = av * rsqrtf(s2);
        __syncthreads();

        float t1 = 0.f, t2 = 0.f, w0 = 0.f;
#pragma unroll 8
        for (int k = 0; k < 64; k++) {
            t1 += th1r[p * 64 + k] * fz[k];
            t2 += th1c[p * 64 + k] * fz[k];
            w0 += th2rc[p * 64 + k] * fcraw[k];
        }
        ws[WS_T1R + p] = t1;
        ws[WS_T1C + p] = t2;
        ws[WS_W + p] = t1 + w0;

        sh4a[p] = th4rr[p];
        sh4b[p] = th4rc[p];
        __syncthreads();
        float a = 0.f, bb = 0.f, g = 0.f, d = 0.f;
#pragma unroll 8
        for (int k = 0; k < 64; k++) {
            float t4 = sh4a[k];
            a  += th3rr[p * 64 + k] * fmaxf(t4, 0.f);
            bb += th3rr[p * 64 + k] * fmaxf(-t4, 0.f);
            float t5 = sh4b[k];
            g  += th3rc[p * 64 + k] * fmaxf(t5, 0.f);
            d  += th3rc[p * 64 + k] * fmaxf(-t5, 0.f);
        }
        ws[WS_AL + p] = a; ws[WS_BE + p] = bb;
        ws[WS_GA + p] = g; ws[WS_DE + p] = d;
        __syncthreads();
        sh4a[p] = th4cr[p];
        __syncthreads();
        float e1 = 0.f, e2 = 0.f;
#pragma unroll 8
        for (int k = 0; k < 64; k++) {
            float t6 = sh4a[k];
            e1 += th3cr[p * 64 + k] * fmaxf(t6, 0.f);
            e2 += th3cr[p * 64 + k] * fmaxf(-t6, 0.f);
        }
        ws[WS_ECP + p] = e1; ws[WS_ECN + p] = e2;

#pragma unroll
        for (int i = 0; i < 16; i++) {
            int idx = tid * 16 + i;
            float f = th2rr[idx];
            unsigned short h = f2bf(f);
            R2H[idx] = h;
            R2L[idx] = f2bf(f - bf2f(h));
        }
        return;
    }

    __shared__ float gsh[64];
    __shared__ float wsh2[2];
    if (tid < 64) gsh[tid] = 0.f;
    if (tid < 2) wsh2[tid] = 0.f;
    __syncthreads();

    float cv = (lane < 63) ? c[lane] : 0.f;
    float cn2 = waveReduceSum(cv * cv);
    float fcnl = cv * rsqrtf(cn2);

    int gw = blockIdx.x * 4 + wid;   // 0..511
    float gl = 0.f, lp = 0.f, ln = 0.f;
    for (int r = gw; r < 8192; r += 512) {
        if (r < 8000) {
            float val = (lane < 63) ? A[r * 63 + lane] : b[r];
            float s2 = waveReduceSum(val * val);
            float f = val * rsqrtf(s2);
            unsigned short h = f2bf(f);
            Fh[r * 64 + lane] = h;
            Fl[r * 64 + lane] = f2bf(f - bf2f(h));
            gl += f;
            float w = waveReduceSum(f * fcnl);
            if (lane == 0) {
                ws[WS_RNORM + r] = sqrtf(s2);
                lp += fmaxf(w, 0.f); ln += fmaxf(-w, 0.f);
            }
        } else {
            Fh[r * 64 + lane] = 0;
            Fl[r * 64 + lane] = 0;
        }
    }
    atomicAdd(&gsh[lane], gl);
    if (lane == 0) { atomicAdd(&wsh2[0], lp); atomicAdd(&wsh2[1], ln); }
    __syncthreads();
    if (tid < 64) ws[WS_GPART + blockIdx.x * 64 + tid] = gsh[tid];
    if (tid == 64) ws[WS_WPART + blockIdx.x * 2 + 0] = wsh2[0];
    if (tid == 65) ws[WS_WPART + blockIdx.x * 2 + 1] = wsh2[1];
}

// K2: MFMA gram row-sums. grid (32,32), block 256.
__global__ __launch_bounds__(256) void k_gram(
    const unsigned short* __restrict__ Fh, const unsigned short* __restrict__ Fl,
    float* __restrict__ ws)
{
    int tid = threadIdx.x, lane = tid & 63, wid = tid >> 6;
    int m = lane & 15, quad = lane >> 4;
    int vbase = blockIdx.x * 256 + wid * 64;

    short8 AH[8], AL[8];
#pragma unroll
    for (int pt = 0; pt < 4; pt++)
#pragma unroll
        for (int q = 0; q < 2; q++) {
            int off = (vbase + pt * 16 + m) * 64 + q * 32 + quad * 8;
            AH[pt * 2 + q] = *(const short8*)(Fh + off);
            AL[pt * 2 + q] = *(const short8*)(Fl + off);
        }
    float srr[16];
#pragma unroll
    for (int i = 0; i < 16; i++) srr[i] = 0.f;

    const int y = blockIdx.y;                  // tiles y + 32k, k=0..15
    const int boff = m * 64 + quad * 8;
    short8 B0h[2], B0l[2], B1h[2], B1l[2];
#pragma unroll
    for (int q = 0; q < 2; q++) {
        B0h[q] = *(const short8*)(Fh + y * 16 * 64 + boff + q * 32);
        B0l[q] = *(const short8*)(Fl + y * 16 * 64 + boff + q * 32);
    }
#pragma unroll 1
    for (int ii = 0; ii < 8; ii++) {
        int tB1 = y + 64 * ii + 32;
#pragma unroll
        for (int q = 0; q < 2; q++) {
            B1h[q] = *(const short8*)(Fh + tB1 * 16 * 64 + boff + q * 32);
            B1l[q] = *(const short8*)(Fl + tB1 * 16 * 64 + boff + q * 32);
        }
#pragma unroll
        for (int pt = 0; pt < 4; pt++) {
            f32x4 a = {0.f, 0.f, 0.f, 0.f};
#pragma unroll
            for (int q = 0; q < 2; q++) {
                a = __builtin_amdgcn_mfma_f32_16x16x32_bf16(AH[pt*2+q], B0h[q], a, 0, 0, 0);
                a = __builtin_amdgcn_mfma_f32_16x16x32_bf16(AH[pt*2+q], B0l[q], a, 0, 0, 0);
                a = __builtin_amdgcn_mfma_f32_16x16x32_bf16(AL[pt*2+q], B0h[q], a, 0, 0, 0);
            }
#pragma unroll
            for (int r = 0; r < 4; r++) srr[pt*4+r] += fmaxf(a[r], 0.f);
        }
        if (ii < 7) {
            int tB0 = y + 64 * ii + 64;
#pragma unroll
            for (int q = 0; q < 2; q++) {
                B0h[q] = *(const short8*)(Fh + tB0 * 16 * 64 + boff + q * 32);
                B0l[q] = *(const short8*)(Fl + tB0 * 16 * 64 + boff + q * 32);
            }
        }
#pragma unroll
        for (int pt = 0; pt < 4; pt++) {
            f32x4 a = {0.f, 0.f, 0.f, 0.f};
#pragma unroll
            for (int q = 0; q < 2; q++) {
                a = __builtin_amdgcn_mfma_f32_16x16x32_bf16(AH[pt*2+q], B1h[q], a, 0, 0, 0);
                a = __builtin_amdgcn_mfma_f32_16x16x32_bf16(AH[pt*2+q], B1l[q], a, 0, 0, 0);
                a = __builtin_amdgcn_mfma_f32_16x16x32_bf16(AL[pt*2+q], B1h[q], a, 0, 0, 0);
            }
#pragma unroll
            for (int r = 0; r < 4; r++) srr[pt*4+r] += fmaxf(a[r], 0.f);
        }
    }
#pragma unroll
    for (int pt = 0; pt < 4; pt++)
#pragma unroll
        for (int r = 0; r < 4; r++) {
            float s = srr[pt * 4 + r];
#pragma unroll
            for (int mm = 8; mm >= 1; mm >>= 1) s += __shfl_xor(s, mm, 64);
            if (m == 0)
                ws[WS_SPART + y * 8192 + vbase + pt * 16 + quad * 4 + r] = s;
        }
}

// K2b: reduce partials; edge terms; in-place mu hi/lo. grid 125 x 256.
__global__ __launch_bounds__(256) void k_e4(
    const float* __restrict__ c, float* __restrict__ ws,
    unsigned short* __restrict__ MH, unsigned short* __restrict__ ML)
{
    __shared__ float fcnS[64], gS[64], sprow[64], red[256];
    int tid = threadIdx.x, lane = tid & 63, wid = tid >> 6;

    float cv = (lane < 63) ? c[lane] : 0.f;
    float cn2 = waveReduceSum(cv * cv);
    if (wid == 0) fcnS[lane] = cv * rsqrtf(cn2);

    float gv = 0.f;
#pragma unroll 8
    for (int blk = wid * 32; blk < wid * 32 + 32; blk++)
        gv += ws[WS_GPART + blk * 64 + lane];
    red[tid] = gv;
    __syncthreads();
    if (tid < 64) gS[tid] = red[tid] + red[64 + tid] + red[128 + tid] + red[192 + tid];
    if (wid == 1) {
        float wp = ws[WS_WPART + lane * 2] + ws[WS_WPART + (lane + 64) * 2];
        wp = waveReduceSum(wp);
        if (lane == 0) ws[WS_WSUM] = wp;       // same value from every block
    }
    if (wid == 2) {
        float wn = ws[WS_WPART + lane * 2 + 1] + ws[WS_WPART + (lane + 64) * 2 + 1];
        wn = waveReduceSum(wn);
        if (lane == 0) ws[WS_WSUM + 1] = wn;
    }
    int v0 = blockIdx.x * 64;
    float sv = 0.f;
#pragma unroll
    for (int y = wid * 8; y < wid * 8 + 8; y++)
        sv += ws[WS_SPART + y * 8192 + v0 + lane];
    __syncthreads();
    red[tid] = sv;
    __syncthreads();
    if (tid < 64) sprow[tid] = red[tid] + red[64 + tid] + red[128 + tid] + red[192 + tid];
    __syncthreads();

    for (int i2 = 0; i2 < 16; i2++) {
        int i = wid * 16 + i2;
        int v = v0 + i;
        unsigned short fh = MH[v * 64 + lane];
        unsigned short fl = ML[v * 64 + lane];
        float fr = bf2f(fh) + bf2f(fl);
        float dw = waveReduceSum(fr * fcnS[lane]);
        float dg = waveReduceSum(fr * gS[lane]);
        if (lane == 0) {
            float spv = sprow[i];
            float4 e;
            e.x = spv - 1.0f;          // remove diagonal relu(1)
            e.y = spv - dg;            // relu(-x) = relu(x) - x
            e.z = fmaxf(dw, 0.f);
            e.w = fmaxf(-dw, 0.f);
            *(float4*)(ws + WS_E4 + v * 4) = e;
        }
        float rnv = ws[WS_RNORM + v];
        float x = fr * rnv;
        unsigned short h = f2bf(x);
        MH[v * 64 + lane] = h;
        ML[v * 64 + lane] = f2bf(x - bf2f(h));
    }
}

// K3: one MFMA recurrence sweep; prev-sweep column update fused (4-wave parallel).
__global__ __launch_bounds__(256) void k_iter(
    const float* __restrict__ th2cr, const float* __restrict__ th2rc,
    const int* __restrict__ zp, float* __restrict__ ws,
    unsigned short* __restrict__ MH, unsigned short* __restrict__ ML,
    const unsigned short* __restrict__ R2H, const unsigned short* __restrict__ R2L,
    int t)
{
    __shared__ __align__(16) float wsh[64], alS[64], beS[64], gaS[64], deS[64];
    __shared__ float red[256], Ssh[64], ysh[64], colp[256];
    int tid = threadIdx.x, lane = tid & 63, wid = tid >> 6;
    int m = lane & 15, quad = lane >> 4;
    int v = (blockIdx.x * 4 + wid) * 16 + m;

    if (tid < 64) {
        alS[tid] = ws[WS_AL + tid]; beS[tid] = ws[WS_BE + tid];
        gaS[tid] = ws[WS_GA + tid]; deS[tid] = ws[WS_DE + tid];
    }
    if (t == 0) {
        if (tid >= 64 && tid < 128) wsh[tid - 64] = ws[WS_W + tid - 64];
        __syncthreads();
    } else {
        float s = 0.f;
        for (int blk = wid; blk < 125; blk += 4)
            s += ws[WS_CPART + (t - 1) * 8000 + blk * 64 + lane];
        red[tid] = s;
        __syncthreads();
        if (tid < 64) Ssh[tid] = red[tid] + red[64 + tid] + red[128 + tid] + red[192 + tid];
        __syncthreads();
        {
            int p = wid * 16 + m;
            float acc = 0.f;
            const float4* rowp = (const float4*)(th2cr + p * 64 + quad * 16);
#pragma unroll
            for (int kk = 0; kk < 4; kk++) {
                float4 r4 = rowp[kk];
                acc += r4.x * Ssh[quad * 16 + 4 * kk]     + r4.y * Ssh[quad * 16 + 4 * kk + 1]
                     + r4.z * Ssh[quad * 16 + 4 * kk + 2] + r4.w * Ssh[quad * 16 + 4 * kk + 3];
            }
            acc += __shfl_xor(acc, 16, 64);
            acc += __shfl_xor(acc, 32, 64);
            if (quad == 0)
                ysh[p] = fmaxf(acc + ws[WS_T1C + p] + ws[WS_WSUM] * ws[WS_ECP + p]
                               + ws[WS_WSUM + 1] * ws[WS_ECN + p], 0.f);
        }
        __syncthreads();
        {
            int p = wid * 16 + m;
            float acc = 0.f;
            const float4* rowp = (const float4*)(th2rc + p * 64 + quad * 16);
#pragma unroll
            for (int kk = 0; kk < 4; kk++) {
                float4 r4 = rowp[kk];
                acc += r4.x * ysh[quad * 16 + 4 * kk]     + r4.y * ysh[quad * 16 + 4 * kk + 1]
                     + r4.z * ysh[quad * 16 + 4 * kk + 2] + r4.w * ysh[quad * 16 + 4 * kk + 3];
            }
            acc += __shfl_xor(acc, 16, 64);
            acc += __shfl_xor(acc, 32, 64);
            if (quad == 0) wsh[p] = acc + ws[WS_T1R + p];
        }
        __syncthreads();
    }

    short8 RH[8], RL[8];
#pragma unroll
    for (int pt = 0; pt < 4; pt++)
#pragma unroll
        for (int q = 0; q < 2; q++) {
            int off = (pt * 16 + m) * 64 + q * 32 + quad * 8;
            RH[pt * 2 + q] = *(const short8*)(R2H + off);
            RL[pt * 2 + q] = *(const short8*)(R2L + off);
        }
    short8 BH[2], BL[2];
#pragma unroll
    for (int q = 0; q < 2; q++) {
        BH[q] = *(const short8*)(MH + v * 64 + q * 32 + quad * 8);
        BL[q] = *(const short8*)(ML + v * 64 + q * 32 + quad * 8);
    }
    float4 e = *(const float4*)(ws + WS_E4 + v * 4);
    int z = zp[0];

#pragma unroll
    for (int pt = 0; pt < 4; pt++) {
        f32x4 a = {0.f, 0.f, 0.f, 0.f};
#pragma unroll
        for (int q = 0; q < 2; q++) {
            a = __builtin_amdgcn_mfma_f32_16x16x32_bf16(RH[pt*2+q], BH[q], a, 0, 0, 0);
            a = __builtin_amdgcn_mfma_f32_16x16x32_bf16(RH[pt*2+q], BL[q], a, 0, 0, 0);
            a = __builtin_amdgcn_mfma_f32_16x16x32_bf16(RL[pt*2+q], BH[q], a, 0, 0, 0);
        }
        int pbase = pt * 16 + quad * 4;
        float4 w4 = *(const float4*)(wsh + pbase);
        float4 a4 = *(const float4*)(alS + pbase);
        float4 b4 = *(const float4*)(beS + pbase);
        float4 g4 = *(const float4*)(gaS + pbase);
        float4 d4 = *(const float4*)(deS + pbase);
        float v0 = fmaxf(a[0] + w4.x + a4.x*e.x + b4.x*e.y + g4.x*e.z + d4.x*e.w, 0.f);
        float v1 = fmaxf(a[1] + w4.y + a4.y*e.x + b4.y*e.y + g4.y*e.z + d4.y*e.w, 0.f);
        float v2 = fmaxf(a[2] + w4.z + a4.z*e.x + b4.z*e.y + g4.z*e.z + d4.z*e.w, 0.f);
        float v3 = fmaxf(a[3] + w4.w + a4.w*e.x + b4.w*e.y + g4.w*e.z + d4.w*e.w, 0.f);
        ushort4 h4, l4;
        h4.x = f2bf(v0); l4.x = f2bf(v0 - bf2f(h4.x));
        h4.y = f2bf(v1); l4.y = f2bf(v1 - bf2f(h4.y));
        h4.z = f2bf(v2); l4.z = f2bf(v2 - bf2f(h4.z));
        h4.w = f2bf(v3); l4.w = f2bf(v3 - bf2f(h4.w));
        *(ushort4*)(MH + v * 64 + pbase) = h4;
        *(ushort4*)(ML + v * 64 + pbase) = l4;
        float c0 = v0, c1 = v1, c2 = v2, c3 = v3;
#pragma unroll
        for (int mm = 1; mm < 16; mm <<= 1) {
            c0 += __shfl_xor(c0, mm, 64);
            c1 += __shfl_xor(c1, mm, 64);
            c2 += __shfl_xor(c2, mm, 64);
            c3 += __shfl_xor(c3, mm, 64);
        }
        if (m == 0) {
            colp[wid * 64 + pbase + 0] = c0;
            colp[wid * 64 + pbase + 1] = c1;
            colp[wid * 64 + pbase + 2] = c2;
            colp[wid * 64 + pbase + 3] = c3;
        }
        if (t == 4 && v == z) {
            float4 o; o.x = v0; o.y = v1; o.z = v2; o.w = v3;
            *(float4*)(ws + WS_MUZ + pbase) = o;
        }
    }
    __syncthreads();
    if (tid < 64)
        ws[WS_CPART + t * 8000 + blockIdx.x * 64 + tid] =
            colp[tid] + colp[64 + tid] + colp[128 + tid] + colp[192 + tid];
}

// K4: reduce last colsum partials + final column update + head. 1x256.
__global__ __launch_bounds__(256) void k_head(
    const float* __restrict__ th2cr,
    const float* __restrict__ th6r, const float* __restrict__ th6c, const float* __restrict__ th7,
    const float* __restrict__ W8, const float* __restrict__ b8,
    float* __restrict__ ws, float* __restrict__ out)
{
    int tid = threadIdx.x, lane = tid & 63, wid = tid >> 6;
    __shared__ float red[256], S[64], y[64], feat[128];
    float s = 0.f;
    for (int blk = wid; blk < 125; blk += 4)
        s += ws[WS_CPART + 4 * 8000 + blk * 64 + lane];
    red[tid] = s;
    __syncthreads();
    if (tid < 64) S[tid] = red[tid] + red[64 + tid] + red[128 + tid] + red[192 + tid];
    __syncthreads();
    int p = tid;
    if (p < 64) {
        float acc = ws[WS_T1C + p] + ws[WS_WSUM] * ws[WS_ECP + p]
                  + ws[WS_WSUM + 1] * ws[WS_ECN + p];
#pragma unroll 8
        for (int k = 0; k < 64; k++) acc += th2cr[p * 64 + k] * S[k];
        y[p] = fmaxf(acc, 0.f);
    }
    __syncthreads();
    if (p < 64) {
        float t6 = 0.f, t7 = 0.f;
#pragma unroll 8
        for (int k = 0; k < 64; k++) {
            t6 += th6r[p * 64 + k] * S[k] + th6c[p * 64 + k] * y[k];
            t7 += th7[p * 64 + k] * ws[WS_MUZ + k];
        }
        feat[p] = 1.f / (1.f + expf(-t6));
        feat[64 + p] = 1.f / (1.f + expf(-t7));
    }
    __syncthreads();
    if (p < 2) {
        float o = b8[p];
        for (int i = 0; i < 128; i++) o += W8[p * 128 + i] * feat[i];
        out[p] = o;
    }
}

extern "C" void kernel_launch(void* const* d_in, const int* in_sizes, int n_in,
                              void* d_out, int out_size, void* d_ws, size_t ws_size,
                              hipStream_t stream) {
    (void)in_sizes; (void)n_in; (void)out_size; (void)ws_size;
    const float* A     = (const float*)d_in[0];
    const float* b     = (const float*)d_in[1];
    const float* c     = (const float*)d_in[2];
    const float* th1r  = (const float*)d_in[3];
    const float* th1c  = (const float*)d_in[4];
    const float* th2rr = (const float*)d_in[5];
    const float* th2rc = (const float*)d_in[6];
    const float* th2cr = (const float*)d_in[7];
    const float* th3rr = (const float*)d_in[8];
    const float* th3rc = (const float*)d_in[9];
    const float* th3cr = (const float*)d_in[10];
    const float* th4rr = (const float*)d_in[11];
    const float* th4rc = (const float*)d_in[12];
    const float* th4cr = (const float*)d_in[13];
    const float* th6r  = (const float*)d_in[14];
    const float* th6c  = (const float*)d_in[15];
    const float* th7   = (const float*)d_in[16];
    const float* W8    = (const float*)d_in[17];
    const float* b8    = (const float*)d_in[18];
    const int*   zp    = (const int*)d_in[19];
    float* ws  = (float*)d_ws;
    float* out = (float*)d_out;
    unsigned short* Fh  = (unsigned short*)(ws + WS_FH);
    unsigned short* Fl  = (unsigned short*)(ws + WS_FL);
    unsigned short* R2H = (unsigned short*)(ws + WS_R2H);
    unsigned short* R2L = (unsigned short*)(ws + WS_R2L);

    k_fr<<<129, 256, 0, stream>>>(A, b, c, th1r, th1c, th2rr, th2rc, th3rr, th3rc,
                                  th3cr, th4rr, th4rc, th4cr, zp, Fh, Fl, R2H, R2L, ws);
    k_gram<<<dim3(32, 32), 256, 0, stream>>>(Fh, Fl, ws);
    k_e4<<<125, 256, 0, stream>>>(c, ws, Fh, Fl);
    for (int t = 0; t < 5; t++)
        k_iter<<<125, 256, 0, stream>>>(th2cr, th2rc, zp, ws, Fh, Fl, R2H, R2L, t);
    k_head<<<1, 256, 0, stream>>>(th2cr, th6r, th6c, th7, W8, b8, ws, out);
}